// Round 1
// baseline (6595.055 us; speedup 1.0000x reference)
//
#include <hip/hip_runtime.h>
#include <hip/hip_bf16.h>

#define H 128
#define NGRAPH 64
#define NLAYERS 2
#define TM 32

// ---------------- encoder: h[i][j] = x[i]*enc_w[j] + enc_b[j] ----------------
__global__ void enc_kernel(const float* __restrict__ x, const float* __restrict__ w,
                           const float* __restrict__ b, float* __restrict__ h, int n) {
    int t = blockIdx.x * blockDim.x + threadIdx.x;
    int i = t >> 5;            // node
    int c = (t & 31) << 2;     // feature*4
    if (i >= n) return;
    float xv = x[i];
    float4 wv = *(const float4*)(w + c);
    float4 bv = *(const float4*)(b + c);
    float4 o;
    o.x = xv * wv.x + bv.x;
    o.y = xv * wv.y + bv.y;
    o.z = xv * wv.z + bv.z;
    o.w = xv * wv.w + bv.w;
    *(float4*)(h + (size_t)i * H + c) = o;
}

// ------------- edge pass: aggr[dst] += relu(h[src] + ea*ew + ebias) ----------
__global__ void edge_kernel(const float* __restrict__ h, const int* __restrict__ ei,
                            const float* __restrict__ ea, const float* __restrict__ ew,
                            const float* __restrict__ eb, float* __restrict__ aggr, int ne) {
    int t = blockIdx.x * blockDim.x + threadIdx.x;
    int e = t >> 5;            // edge (32 threads/edge)
    int c = (t & 31) << 2;     // feature*4
    if (e >= ne) return;
    int src = ei[e];
    int dst = ei[ne + e];
    float a = ea[e];
    float4 wv = *(const float4*)(ew + c);
    float4 bv = *(const float4*)(eb + c);
    float4 hv = *(const float4*)(h + (size_t)src * H + c);
    float4 m;
    m.x = fmaxf(hv.x + a * wv.x + bv.x, 0.f);
    m.y = fmaxf(hv.y + a * wv.y + bv.y, 0.f);
    m.z = fmaxf(hv.z + a * wv.z + bv.z, 0.f);
    m.w = fmaxf(hv.w + a * wv.w + bv.w, 0.f);
    float* ap = aggr + (size_t)dst * H + c;
    atomicAdd(ap + 0, m.x);
    atomicAdd(ap + 1, m.y);
    atomicAdd(ap + 2, m.z);
    atomicAdd(ap + 3, m.w);
}

// ---- fused node MLP: h = relu(BN(relu(z@w1+b1)@w2+b2)), z=(1+eps)h+aggr ----
__global__ __launch_bounds__(256) void mlp_kernel(
    float* __restrict__ h, const float* __restrict__ aggr,
    const float* __restrict__ w1, const float* __restrict__ b1,
    const float* __restrict__ w2, const float* __restrict__ b2,
    const float* __restrict__ gamma, const float* __restrict__ beta,
    const float* __restrict__ mean, const float* __restrict__ var,
    const float* __restrict__ epsp, int layer, int n) {
    __shared__ float zs[TM][H];   // 16 KB
    __shared__ float ts[TM][H];   // 16 KB
    const int tid = threadIdx.x;
    const int row0 = blockIdx.x * TM;
    const float ev = 1.0f + epsp[layer];

    // stage z = (1+eps)*h + aggr   (TM*H floats = 1024 float4s, 256 threads)
    #pragma unroll
    for (int it = 0; it < 4; ++it) {
        int idx = tid + it * 256;
        int r = idx >> 5;
        int c = (idx & 31) << 2;
        int gr = row0 + r;
        float4 v = make_float4(0.f, 0.f, 0.f, 0.f);
        if (gr < n) {
            float4 hv = *(const float4*)(h + (size_t)gr * H + c);
            float4 av = *(const float4*)(aggr + (size_t)gr * H + c);
            v.x = ev * hv.x + av.x;
            v.y = ev * hv.y + av.y;
            v.z = ev * hv.z + av.z;
            v.w = ev * hv.w + av.w;
        }
        *(float4*)(&zs[r][c]) = v;
    }
    __syncthreads();

    const int tx = tid & 31;
    const int ty = tid >> 5;
    const int c0 = tx << 2;
    const int r0 = ty << 2;

    // ---------- GEMM1: t = relu(z @ w1 + b1) ----------
    float acc[4][4];
    #pragma unroll
    for (int i = 0; i < 4; ++i)
        #pragma unroll
        for (int j = 0; j < 4; ++j) acc[i][j] = 0.f;

    for (int k = 0; k < H; k += 4) {
        float zr[4][4];
        #pragma unroll
        for (int i = 0; i < 4; ++i)
            *(float4*)zr[i] = *(const float4*)(&zs[r0 + i][k]);
        float wr[4][4];
        const float* wp = w1 + (size_t)k * H + c0;
        #pragma unroll
        for (int kk = 0; kk < 4; ++kk)
            *(float4*)wr[kk] = *(const float4*)(wp + (size_t)kk * H);
        #pragma unroll
        for (int kk = 0; kk < 4; ++kk)
            #pragma unroll
            for (int i = 0; i < 4; ++i)
                #pragma unroll
                for (int j = 0; j < 4; ++j)
                    acc[i][j] += zr[i][kk] * wr[kk][j];
    }
    {
        float bb[4];
        *(float4*)bb = *(const float4*)(b1 + c0);
        #pragma unroll
        for (int i = 0; i < 4; ++i) {
            float4 o;
            o.x = fmaxf(acc[i][0] + bb[0], 0.f);
            o.y = fmaxf(acc[i][1] + bb[1], 0.f);
            o.z = fmaxf(acc[i][2] + bb[2], 0.f);
            o.w = fmaxf(acc[i][3] + bb[3], 0.f);
            *(float4*)(&ts[r0 + i][c0]) = o;
        }
    }
    __syncthreads();

    // ---------- GEMM2: z2 = t @ w2 + b2, then BN + relu ----------
    float acc2[4][4];
    #pragma unroll
    for (int i = 0; i < 4; ++i)
        #pragma unroll
        for (int j = 0; j < 4; ++j) acc2[i][j] = 0.f;

    for (int k = 0; k < H; k += 4) {
        float tr[4][4];
        #pragma unroll
        for (int i = 0; i < 4; ++i)
            *(float4*)tr[i] = *(const float4*)(&ts[r0 + i][k]);
        float wr[4][4];
        const float* wp = w2 + (size_t)k * H + c0;
        #pragma unroll
        for (int kk = 0; kk < 4; ++kk)
            *(float4*)wr[kk] = *(const float4*)(wp + (size_t)kk * H);
        #pragma unroll
        for (int kk = 0; kk < 4; ++kk)
            #pragma unroll
            for (int i = 0; i < 4; ++i)
                #pragma unroll
                for (int j = 0; j < 4; ++j)
                    acc2[i][j] += tr[i][kk] * wr[kk][j];
    }
    {
        float bb[4], gm[4], bt[4], mn[4], vr[4];
        *(float4*)bb = *(const float4*)(b2 + c0);
        *(float4*)gm = *(const float4*)(gamma + c0);
        *(float4*)bt = *(const float4*)(beta + c0);
        *(float4*)mn = *(const float4*)(mean + c0);
        *(float4*)vr = *(const float4*)(var + c0);
        float sc[4];
        #pragma unroll
        for (int j = 0; j < 4; ++j) sc[j] = gm[j] * rsqrtf(vr[j] + 1e-5f);
        #pragma unroll
        for (int i = 0; i < 4; ++i) {
            int gr = row0 + r0 + i;
            if (gr < n) {
                float4 o;
                o.x = fmaxf((acc2[i][0] + bb[0] - mn[0]) * sc[0] + bt[0], 0.f);
                o.y = fmaxf((acc2[i][1] + bb[1] - mn[1]) * sc[1] + bt[1], 0.f);
                o.z = fmaxf((acc2[i][2] + bb[2] - mn[2]) * sc[2] + bt[2], 0.f);
                o.w = fmaxf((acc2[i][3] + bb[3] - mn[3]) * sc[3] + bt[3], 0.f);
                *(float4*)(h + (size_t)gr * H + c0) = o;
            }
        }
    }
}

// ---------------- global mean pool (atomic) ----------------
__global__ void pool_kernel(const float* __restrict__ h, const int* __restrict__ batch,
                            float* __restrict__ sums, float* __restrict__ cnts, int n) {
    int t = blockIdx.x * blockDim.x + threadIdx.x;
    int i = t >> 5;
    int c = (t & 31) << 2;
    if (i >= n) return;
    int g = batch[i];
    float4 v = *(const float4*)(h + (size_t)i * H + c);
    float* sp = sums + (size_t)g * H + c;
    atomicAdd(sp + 0, v.x);
    atomicAdd(sp + 1, v.y);
    atomicAdd(sp + 2, v.z);
    atomicAdd(sp + 3, v.w);
    if (c == 0) atomicAdd(cnts + g, 1.0f);
}

// ---------------- classifier: sigmoid(relu(g@w1+b1)@w2+b2) ----------------
__global__ void cls_kernel(const float* __restrict__ sums, const float* __restrict__ cnts,
                           const float* __restrict__ w1, const float* __restrict__ b1,
                           const float* __restrict__ w2, const float* __restrict__ b2,
                           float* __restrict__ out) {
    int g = blockIdx.x;     // 64 graphs
    int m = threadIdx.x;    // 64 mids
    float inv = 1.0f / fmaxf(cnts[g], 1.0f);
    float acc = 0.f;
    for (int k = 0; k < H; ++k) {
        float gk = sums[(size_t)g * H + k] * inv;
        acc += gk * w1[(size_t)k * 64 + m];
    }
    float tm = fmaxf(acc + b1[m], 0.f);
    float p = tm * w2[m];
    #pragma unroll
    for (int off = 32; off > 0; off >>= 1) p += __shfl_down(p, off, 64);
    if (m == 0) out[g] = 1.f / (1.f + expf(-(p + b2[0])));
}

extern "C" void kernel_launch(void* const* d_in, const int* in_sizes, int n_in,
                              void* d_out, int out_size, void* d_ws, size_t ws_size,
                              hipStream_t stream) {
    const float* x      = (const float*)d_in[0];
    const int*   ei     = (const int*)d_in[1];
    const float* ea     = (const float*)d_in[2];
    const int*   batch  = (const int*)d_in[3];
    const float* enc_w  = (const float*)d_in[4];
    const float* enc_b  = (const float*)d_in[5];
    const float* edge_w = (const float*)d_in[6];
    const float* edge_b = (const float*)d_in[7];
    const float* eps    = (const float*)d_in[8];
    const float* mlp_w1 = (const float*)d_in[9];
    const float* mlp_b1 = (const float*)d_in[10];
    const float* mlp_w2 = (const float*)d_in[11];
    const float* mlp_b2 = (const float*)d_in[12];
    const float* bn_g   = (const float*)d_in[13];
    const float* bn_b   = (const float*)d_in[14];
    const float* bn_m   = (const float*)d_in[15];
    const float* bn_v   = (const float*)d_in[16];
    const float* cls_w1 = (const float*)d_in[17];
    const float* cls_b1 = (const float*)d_in[18];
    const float* cls_w2 = (const float*)d_in[19];
    const float* cls_b2 = (const float*)d_in[20];
    float* out = (float*)d_out;

    const int n = in_sizes[0];        // 100000
    const int ne = in_sizes[2];       // 1600000

    float* h    = (float*)d_ws;
    float* aggr = h + (size_t)n * H;
    float* sums = aggr + (size_t)n * H;
    float* cnts = sums + (size_t)NGRAPH * H;

    // zero pool accumulators once
    hipMemsetAsync(sums, 0, (size_t)(NGRAPH * H + NGRAPH) * sizeof(float), stream);

    // encoder
    {
        int threads = n * 32;
        enc_kernel<<<(threads + 255) / 256, 256, 0, stream>>>(x, enc_w, enc_b, h, n);
    }

    for (int l = 0; l < NLAYERS; ++l) {
        hipMemsetAsync(aggr, 0, (size_t)n * H * sizeof(float), stream);
        {
            int threads = ne * 32;
            edge_kernel<<<(threads + 255) / 256, 256, 0, stream>>>(h, ei, ea, edge_w, edge_b,
                                                                   aggr, ne);
        }
        mlp_kernel<<<(n + TM - 1) / TM, 256, 0, stream>>>(
            h, aggr,
            mlp_w1 + (size_t)l * H * H, mlp_b1 + (size_t)l * H,
            mlp_w2 + (size_t)l * H * H, mlp_b2 + (size_t)l * H,
            bn_g + (size_t)l * H, bn_b + (size_t)l * H,
            bn_m + (size_t)l * H, bn_v + (size_t)l * H,
            eps, l, n);
    }

    {
        int threads = n * 32;
        pool_kernel<<<(threads + 255) / 256, 256, 0, stream>>>(h, batch, sums, cnts, n);
    }
    cls_kernel<<<NGRAPH, 64, 0, stream>>>(sums, cnts, cls_w1, cls_b1, cls_w2, cls_b2, out);
}

// Round 2
// 1849.430 us; speedup vs baseline: 3.5660x; 3.5660x over previous
//
#include <hip/hip_runtime.h>
#include <hip/hip_bf16.h>

#define H 128
#define NGRAPH 64
#define NLAYERS 2
#define TM 32

// ---------------- encoder: h[i][j] = x[i]*enc_w[j] + enc_b[j] ----------------
__global__ void enc_kernel(const float* __restrict__ x, const float* __restrict__ w,
                           const float* __restrict__ b, float* __restrict__ h, int n) {
    int t = blockIdx.x * blockDim.x + threadIdx.x;
    int i = t >> 5;            // node
    int c = (t & 31) << 2;     // feature*4
    if (i >= n) return;
    float xv = x[i];
    float4 wv = *(const float4*)(w + c);
    float4 bv = *(const float4*)(b + c);
    float4 o;
    o.x = xv * wv.x + bv.x;
    o.y = xv * wv.y + bv.y;
    o.z = xv * wv.z + bv.z;
    o.w = xv * wv.w + bv.w;
    *(float4*)(h + (size_t)i * H + c) = o;
}

// ---------------- counting-sort by dst: histogram ----------------
__global__ void hist_kernel(const int* __restrict__ ei, int* __restrict__ deg, int ne) {
    int e = blockIdx.x * blockDim.x + threadIdx.x;
    if (e >= ne) return;
    atomicAdd(&deg[ei[ne + e]], 1);
}

// ---------------- counting-sort: exclusive scan (single block, wave scans) ----
__global__ __launch_bounds__(1024) void scan_kernel(const int* __restrict__ deg,
                                                    int* __restrict__ start, int n) {
    __shared__ int wsum[16];
    __shared__ int carry_s;
    const int tid = threadIdx.x;
    const int lane = tid & 63, wid = tid >> 6;
    if (tid == 0) carry_s = 0;
    __syncthreads();
    for (int base = 0; base < n; base += 1024) {
        int idx = base + tid;
        int v = (idx < n) ? deg[idx] : 0;
        int s = v;
        #pragma unroll
        for (int off = 1; off < 64; off <<= 1) {
            int t = __shfl_up(s, off, 64);
            if (lane >= off) s += t;
        }
        if (lane == 63) wsum[wid] = s;
        __syncthreads();
        if (wid == 0 && lane < 16) {
            int ws = wsum[lane];
            #pragma unroll
            for (int off = 1; off < 16; off <<= 1) {
                int t = __shfl_up(ws, off, 64);
                if (lane >= off) ws += t;
            }
            wsum[lane] = ws;
        }
        __syncthreads();
        int wexcl = (wid == 0) ? 0 : wsum[wid - 1];
        int incl = s + wexcl;
        int carry = carry_s;
        if (idx < n) start[idx] = carry + incl - v;
        __syncthreads();
        if (tid == 1023) carry_s = carry + incl;
        __syncthreads();
    }
    if (tid == 0) start[n] = carry_s;
}

// ---------------- counting-sort: scatter edges into dst order ----------------
__global__ void scatter_kernel(const int* __restrict__ ei, const float* __restrict__ ea,
                               const int* __restrict__ start, int* __restrict__ cursor,
                               int* __restrict__ ssrc, float* __restrict__ sea, int ne) {
    int e = blockIdx.x * blockDim.x + threadIdx.x;
    if (e >= ne) return;
    int dst = ei[ne + e];
    int pos = start[dst] + atomicAdd(&cursor[dst], 1);
    ssrc[pos] = ei[e];
    sea[pos] = ea[e];
}

// ---- segment-reduce gather: z[i] = (1+eps)*h[i] + sum_j relu(h[src_j]+e_j) ----
// one 64-lane wave per node, float2 per lane, single non-atomic row write
__global__ __launch_bounds__(256) void aggregate_kernel(
    const float* __restrict__ h, const int* __restrict__ start,
    const int* __restrict__ ssrc, const float* __restrict__ sea,
    const float* __restrict__ ew, const float* __restrict__ eb,
    const float* __restrict__ epsp, int layer,
    float* __restrict__ z, int n) {
    int node = (blockIdx.x * blockDim.x + threadIdx.x) >> 6;
    int lane = threadIdx.x & 63;
    if (node >= n) return;
    int c = lane << 1;
    float2 wv = *(const float2*)(ew + c);
    float2 bv = *(const float2*)(eb + c);
    float2 acc = make_float2(0.f, 0.f);
    int s0 = start[node], s1 = start[node + 1];
    for (int j = s0; j < s1; ++j) {
        int src = ssrc[j];
        float a = sea[j];
        float2 hv = *(const float2*)(h + (size_t)src * H + c);
        acc.x += fmaxf(fmaf(a, wv.x, bv.x) + hv.x, 0.f);
        acc.y += fmaxf(fmaf(a, wv.y, bv.y) + hv.y, 0.f);
    }
    float ev = 1.0f + epsp[layer];
    float2 hv = *(const float2*)(h + (size_t)node * H + c);
    float2 o;
    o.x = fmaf(ev, hv.x, acc.x);
    o.y = fmaf(ev, hv.y, acc.y);
    *(float2*)(z + (size_t)node * H + c) = o;
}

// ---- fused node MLP: h = relu(BN(relu(z@w1+b1)@w2+b2)) ----
__global__ __launch_bounds__(256) void mlp_kernel(
    float* __restrict__ h, const float* __restrict__ z,
    const float* __restrict__ w1, const float* __restrict__ b1,
    const float* __restrict__ w2, const float* __restrict__ b2,
    const float* __restrict__ gamma, const float* __restrict__ beta,
    const float* __restrict__ mean, const float* __restrict__ var, int n) {
    __shared__ float zs[TM][H];   // 16 KB
    __shared__ float ts[TM][H];   // 16 KB
    const int tid = threadIdx.x;
    const int row0 = blockIdx.x * TM;

    // stage z tile (TM*H floats = 1024 float4s, 256 threads)
    #pragma unroll
    for (int it = 0; it < 4; ++it) {
        int idx = tid + it * 256;
        int r = idx >> 5;
        int c = (idx & 31) << 2;
        int gr = row0 + r;
        float4 v = make_float4(0.f, 0.f, 0.f, 0.f);
        if (gr < n) v = *(const float4*)(z + (size_t)gr * H + c);
        *(float4*)(&zs[r][c]) = v;
    }
    __syncthreads();

    const int tx = tid & 31;
    const int ty = tid >> 5;
    const int c0 = tx << 2;
    const int r0 = ty << 2;

    // ---------- GEMM1: t = relu(z @ w1 + b1) ----------
    float acc[4][4];
    #pragma unroll
    for (int i = 0; i < 4; ++i)
        #pragma unroll
        for (int j = 0; j < 4; ++j) acc[i][j] = 0.f;

    for (int k = 0; k < H; k += 4) {
        float zr[4][4];
        #pragma unroll
        for (int i = 0; i < 4; ++i)
            *(float4*)zr[i] = *(const float4*)(&zs[r0 + i][k]);
        float wr[4][4];
        const float* wp = w1 + (size_t)k * H + c0;
        #pragma unroll
        for (int kk = 0; kk < 4; ++kk)
            *(float4*)wr[kk] = *(const float4*)(wp + (size_t)kk * H);
        #pragma unroll
        for (int kk = 0; kk < 4; ++kk)
            #pragma unroll
            for (int i = 0; i < 4; ++i)
                #pragma unroll
                for (int j = 0; j < 4; ++j)
                    acc[i][j] += zr[i][kk] * wr[kk][j];
    }
    {
        float bb[4];
        *(float4*)bb = *(const float4*)(b1 + c0);
        #pragma unroll
        for (int i = 0; i < 4; ++i) {
            float4 o;
            o.x = fmaxf(acc[i][0] + bb[0], 0.f);
            o.y = fmaxf(acc[i][1] + bb[1], 0.f);
            o.z = fmaxf(acc[i][2] + bb[2], 0.f);
            o.w = fmaxf(acc[i][3] + bb[3], 0.f);
            *(float4*)(&ts[r0 + i][c0]) = o;
        }
    }
    __syncthreads();

    // ---------- GEMM2: z2 = t @ w2 + b2, then BN + relu ----------
    float acc2[4][4];
    #pragma unroll
    for (int i = 0; i < 4; ++i)
        #pragma unroll
        for (int j = 0; j < 4; ++j) acc2[i][j] = 0.f;

    for (int k = 0; k < H; k += 4) {
        float tr[4][4];
        #pragma unroll
        for (int i = 0; i < 4; ++i)
            *(float4*)tr[i] = *(const float4*)(&ts[r0 + i][k]);
        float wr[4][4];
        const float* wp = w2 + (size_t)k * H + c0;
        #pragma unroll
        for (int kk = 0; kk < 4; ++kk)
            *(float4*)wr[kk] = *(const float4*)(wp + (size_t)kk * H);
        #pragma unroll
        for (int kk = 0; kk < 4; ++kk)
            #pragma unroll
            for (int i = 0; i < 4; ++i)
                #pragma unroll
                for (int j = 0; j < 4; ++j)
                    acc2[i][j] += tr[i][kk] * wr[kk][j];
    }
    {
        float bb[4], gm[4], bt[4], mn[4], vr[4];
        *(float4*)bb = *(const float4*)(b2 + c0);
        *(float4*)gm = *(const float4*)(gamma + c0);
        *(float4*)bt = *(const float4*)(beta + c0);
        *(float4*)mn = *(const float4*)(mean + c0);
        *(float4*)vr = *(const float4*)(var + c0);
        float sc[4];
        #pragma unroll
        for (int j = 0; j < 4; ++j) sc[j] = gm[j] * rsqrtf(vr[j] + 1e-5f);
        #pragma unroll
        for (int i = 0; i < 4; ++i) {
            int gr = row0 + r0 + i;
            if (gr < n) {
                float4 o;
                o.x = fmaxf((acc2[i][0] + bb[0] - mn[0]) * sc[0] + bt[0], 0.f);
                o.y = fmaxf((acc2[i][1] + bb[1] - mn[1]) * sc[1] + bt[1], 0.f);
                o.z = fmaxf((acc2[i][2] + bb[2] - mn[2]) * sc[2] + bt[2], 0.f);
                o.w = fmaxf((acc2[i][3] + bb[3] - mn[3]) * sc[3] + bt[3], 0.f);
                *(float4*)(h + (size_t)gr * H + c0) = o;
            }
        }
    }
}

// ---------------- global mean pool (atomic) ----------------
__global__ void pool_kernel(const float* __restrict__ h, const int* __restrict__ batch,
                            float* __restrict__ sums, float* __restrict__ cnts, int n) {
    int t = blockIdx.x * blockDim.x + threadIdx.x;
    int i = t >> 5;
    int c = (t & 31) << 2;
    if (i >= n) return;
    int g = batch[i];
    float4 v = *(const float4*)(h + (size_t)i * H + c);
    float* sp = sums + (size_t)g * H + c;
    atomicAdd(sp + 0, v.x);
    atomicAdd(sp + 1, v.y);
    atomicAdd(sp + 2, v.z);
    atomicAdd(sp + 3, v.w);
    if (c == 0) atomicAdd(cnts + g, 1.0f);
}

// ---------------- classifier: sigmoid(relu(g@w1+b1)@w2+b2) ----------------
__global__ void cls_kernel(const float* __restrict__ sums, const float* __restrict__ cnts,
                           const float* __restrict__ w1, const float* __restrict__ b1,
                           const float* __restrict__ w2, const float* __restrict__ b2,
                           float* __restrict__ out) {
    int g = blockIdx.x;     // 64 graphs
    int m = threadIdx.x;    // 64 mids
    float inv = 1.0f / fmaxf(cnts[g], 1.0f);
    float acc = 0.f;
    for (int k = 0; k < H; ++k) {
        float gk = sums[(size_t)g * H + k] * inv;
        acc += gk * w1[(size_t)k * 64 + m];
    }
    float tm = fmaxf(acc + b1[m], 0.f);
    float p = tm * w2[m];
    #pragma unroll
    for (int off = 32; off > 0; off >>= 1) p += __shfl_down(p, off, 64);
    if (m == 0) out[g] = 1.f / (1.f + expf(-(p + b2[0])));
}

extern "C" void kernel_launch(void* const* d_in, const int* in_sizes, int n_in,
                              void* d_out, int out_size, void* d_ws, size_t ws_size,
                              hipStream_t stream) {
    const float* x      = (const float*)d_in[0];
    const int*   ei     = (const int*)d_in[1];
    const float* ea     = (const float*)d_in[2];
    const int*   batch  = (const int*)d_in[3];
    const float* enc_w  = (const float*)d_in[4];
    const float* enc_b  = (const float*)d_in[5];
    const float* edge_w = (const float*)d_in[6];
    const float* edge_b = (const float*)d_in[7];
    const float* eps    = (const float*)d_in[8];
    const float* mlp_w1 = (const float*)d_in[9];
    const float* mlp_b1 = (const float*)d_in[10];
    const float* mlp_w2 = (const float*)d_in[11];
    const float* mlp_b2 = (const float*)d_in[12];
    const float* bn_g   = (const float*)d_in[13];
    const float* bn_b   = (const float*)d_in[14];
    const float* bn_m   = (const float*)d_in[15];
    const float* bn_v   = (const float*)d_in[16];
    const float* cls_w1 = (const float*)d_in[17];
    const float* cls_b1 = (const float*)d_in[18];
    const float* cls_w2 = (const float*)d_in[19];
    const float* cls_b2 = (const float*)d_in[20];
    float* out = (float*)d_out;

    const int n = in_sizes[0];        // 100000
    const int ne = in_sizes[2];       // 1600000

    // workspace layout
    float* h      = (float*)d_ws;                       // N*H
    float* z      = h + (size_t)n * H;                  // N*H
    float* sums   = z + (size_t)n * H;                  // G*H
    float* cnts   = sums + (size_t)NGRAPH * H;          // G
    int*   deg    = (int*)(cnts + NGRAPH);              // N
    int*   start  = deg + n;                            // N+1
    int*   cursor = start + n + 1;                      // N
    int*   ssrc   = cursor + n;                         // E
    float* sea    = (float*)(ssrc + ne);                // E

    // zero the accumulators/counters we rely on
    hipMemsetAsync(sums, 0, (size_t)(NGRAPH * H + NGRAPH) * sizeof(float), stream);
    hipMemsetAsync(deg, 0, (size_t)n * sizeof(int), stream);
    hipMemsetAsync(cursor, 0, (size_t)n * sizeof(int), stream);

    // ---- counting sort of edges by dst (once per call; reused both layers) ----
    hist_kernel<<<(ne + 255) / 256, 256, 0, stream>>>(ei, deg, ne);
    scan_kernel<<<1, 1024, 0, stream>>>(deg, start, n);
    scatter_kernel<<<(ne + 255) / 256, 256, 0, stream>>>(ei, ea, start, cursor, ssrc, sea, ne);

    // encoder
    {
        int threads = n * 32;
        enc_kernel<<<(threads + 255) / 256, 256, 0, stream>>>(x, enc_w, enc_b, h, n);
    }

    for (int l = 0; l < NLAYERS; ++l) {
        {
            int threads = n * 64;
            aggregate_kernel<<<(threads + 255) / 256, 256, 0, stream>>>(
                h, start, ssrc, sea, edge_w, edge_b, eps, l, z, n);
        }
        mlp_kernel<<<(n + TM - 1) / TM, 256, 0, stream>>>(
            h, z,
            mlp_w1 + (size_t)l * H * H, mlp_b1 + (size_t)l * H,
            mlp_w2 + (size_t)l * H * H, mlp_b2 + (size_t)l * H,
            bn_g + (size_t)l * H, bn_b + (size_t)l * H,
            bn_m + (size_t)l * H, bn_v + (size_t)l * H, n);
    }

    {
        int threads = n * 32;
        pool_kernel<<<(threads + 255) / 256, 256, 0, stream>>>(h, batch, sums, cnts, n);
    }
    cls_kernel<<<NGRAPH, 64, 0, stream>>>(sums, cnts, cls_w1, cls_b1, cls_w2, cls_b2, out);
}

// Round 3
// 734.800 us; speedup vs baseline: 8.9753x; 2.5169x over previous
//
#include <hip/hip_runtime.h>
#include <hip/hip_bf16.h>

#define H 128
#define NGRAPH 64
#define NLAYERS 2
#define TM 32

// ---------------- encoder: h[i][j] = x[i]*enc_w[j] + enc_b[j] ----------------
__global__ void enc_kernel(const float* __restrict__ x, const float* __restrict__ w,
                           const float* __restrict__ b, float* __restrict__ h, int n) {
    int t = blockIdx.x * blockDim.x + threadIdx.x;
    int i = t >> 5;            // node
    int c = (t & 31) << 2;     // feature*4
    if (i >= n) return;
    float xv = x[i];
    float4 wv = *(const float4*)(w + c);
    float4 bv = *(const float4*)(b + c);
    float4 o;
    o.x = xv * wv.x + bv.x;
    o.y = xv * wv.y + bv.y;
    o.z = xv * wv.z + bv.z;
    o.w = xv * wv.w + bv.w;
    *(float4*)(h + (size_t)i * H + c) = o;
}

// ---------------- counting-sort by dst: histogram ----------------
__global__ void hist_kernel(const int* __restrict__ ei, int* __restrict__ deg, int ne) {
    int e = blockIdx.x * blockDim.x + threadIdx.x;
    if (e >= ne) return;
    atomicAdd(&deg[ei[ne + e]], 1);
}

// -------- hierarchical exclusive scan, level 1: 1024 elems per block --------
__global__ __launch_bounds__(256) void scan1_kernel(const int* __restrict__ deg,
                                                    int* __restrict__ start,
                                                    int* __restrict__ bsum, int n) {
    __shared__ int wsum[4];
    const int t = threadIdx.x;
    const int lane = t & 63;
    const int wid = t >> 6;
    const int base = blockIdx.x * 1024 + t * 4;
    int4 v = make_int4(0, 0, 0, 0);
    if (base + 3 < n) v = *(const int4*)(deg + base);
    else {
        if (base + 0 < n) v.x = deg[base + 0];
        if (base + 1 < n) v.y = deg[base + 1];
        if (base + 2 < n) v.z = deg[base + 2];
    }
    int s = v.x + v.y + v.z + v.w;
    int incl = s;
    #pragma unroll
    for (int off = 1; off < 64; off <<= 1) {
        int u = __shfl_up(incl, off, 64);
        if (lane >= off) incl += u;
    }
    if (lane == 63) wsum[wid] = incl;
    __syncthreads();
    int woff = 0;
    #pragma unroll
    for (int k = 0; k < 4; ++k) if (k < wid) woff += wsum[k];
    int excl = woff + incl - s;
    int4 o;
    o.x = excl;
    o.y = o.x + v.x;
    o.z = o.y + v.y;
    o.w = o.z + v.z;
    if (base + 3 < n) *(int4*)(start + base) = o;
    else {
        if (base + 0 < n) start[base + 0] = o.x;
        if (base + 1 < n) start[base + 1] = o.y;
        if (base + 2 < n) start[base + 2] = o.z;
    }
    if (t == 255) bsum[blockIdx.x] = woff + incl;
}

// -------- scan level 2: scan block sums (nb <= 256), write total to start[n] --
__global__ __launch_bounds__(256) void scan2_kernel(const int* __restrict__ bsum,
                                                    int* __restrict__ bscan,
                                                    int* __restrict__ start, int nb, int n) {
    __shared__ int wsum[4];
    const int t = threadIdx.x;
    const int lane = t & 63;
    const int wid = t >> 6;
    int v = (t < nb) ? bsum[t] : 0;
    int incl = v;
    #pragma unroll
    for (int off = 1; off < 64; off <<= 1) {
        int u = __shfl_up(incl, off, 64);
        if (lane >= off) incl += u;
    }
    if (lane == 63) wsum[wid] = incl;
    __syncthreads();
    int woff = 0;
    #pragma unroll
    for (int k = 0; k < 4; ++k) if (k < wid) woff += wsum[k];
    if (t < nb) bscan[t] = woff + incl - v;
    if (t == 255) start[n] = woff + incl;
}

// -------- scan level 3: add block offsets --------
__global__ void scan3_kernel(int* __restrict__ start, const int* __restrict__ bscan, int n) {
    int i = blockIdx.x * blockDim.x + threadIdx.x;
    if (i < n) start[i] += bscan[i >> 10];
}

// ------- counting-sort: scatter (src, attr) packed into dst order -------
__global__ void scatter_kernel(const int* __restrict__ ei, const float* __restrict__ ea,
                               const int* __restrict__ start, int* __restrict__ cursor,
                               int2* __restrict__ sedge, int ne) {
    int e = blockIdx.x * blockDim.x + threadIdx.x;
    if (e >= ne) return;
    int dst = ei[ne + e];
    int pos = start[dst] + atomicAdd(&cursor[dst], 1);
    int2 p;
    p.x = ei[e];
    p.y = __float_as_int(ea[e]);
    sedge[pos] = p;
}

// ---- segment-reduce gather: z[i] = (1+eps)*h[i] + sum_j relu(h[src_j]+e_j) ----
// one wave per node, float2 per lane, 8-way unrolled edge loop for MLP
__global__ __launch_bounds__(256) void aggregate_kernel(
    const float* __restrict__ h, const int* __restrict__ start,
    const int2* __restrict__ sedge,
    const float* __restrict__ ew, const float* __restrict__ eb,
    const float* __restrict__ epsp, int layer,
    float* __restrict__ z, int n) {
    int node = (blockIdx.x * blockDim.x + threadIdx.x) >> 6;
    int lane = threadIdx.x & 63;
    if (node >= n) return;
    int c = lane << 1;
    float2 wv = *(const float2*)(ew + c);
    float2 bv = *(const float2*)(eb + c);
    float2 acc = make_float2(0.f, 0.f);
    int s0 = start[node], s1 = start[node + 1];
    int j = s0;
    for (; j + 8 <= s1; j += 8) {
        int2 e[8];
        float2 hv[8];
        #pragma unroll
        for (int k = 0; k < 8; ++k) e[k] = sedge[j + k];
        #pragma unroll
        for (int k = 0; k < 8; ++k)
            hv[k] = *(const float2*)(h + (size_t)e[k].x * H + c);
        #pragma unroll
        for (int k = 0; k < 8; ++k) {
            float a = __int_as_float(e[k].y);
            acc.x += fmaxf(fmaf(a, wv.x, bv.x) + hv[k].x, 0.f);
            acc.y += fmaxf(fmaf(a, wv.y, bv.y) + hv[k].y, 0.f);
        }
    }
    for (; j < s1; ++j) {
        int2 e = sedge[j];
        float a = __int_as_float(e.y);
        float2 hv = *(const float2*)(h + (size_t)e.x * H + c);
        acc.x += fmaxf(fmaf(a, wv.x, bv.x) + hv.x, 0.f);
        acc.y += fmaxf(fmaf(a, wv.y, bv.y) + hv.y, 0.f);
    }
    float ev = 1.0f + epsp[layer];
    float2 hv = *(const float2*)(h + (size_t)node * H + c);
    float2 o;
    o.x = fmaf(ev, hv.x, acc.x);
    o.y = fmaf(ev, hv.y, acc.y);
    *(float2*)(z + (size_t)node * H + c) = o;
}

// ---- fused node MLP: h = relu(BN(relu(z@w1+b1)@w2+b2)) ----
__global__ __launch_bounds__(256) void mlp_kernel(
    float* __restrict__ h, const float* __restrict__ z,
    const float* __restrict__ w1, const float* __restrict__ b1,
    const float* __restrict__ w2, const float* __restrict__ b2,
    const float* __restrict__ gamma, const float* __restrict__ beta,
    const float* __restrict__ mean, const float* __restrict__ var, int n) {
    __shared__ float zs[TM][H];   // 16 KB
    __shared__ float ts[TM][H];   // 16 KB
    const int tid = threadIdx.x;
    const int row0 = blockIdx.x * TM;

    #pragma unroll
    for (int it = 0; it < 4; ++it) {
        int idx = tid + it * 256;
        int r = idx >> 5;
        int c = (idx & 31) << 2;
        int gr = row0 + r;
        float4 v = make_float4(0.f, 0.f, 0.f, 0.f);
        if (gr < n) v = *(const float4*)(z + (size_t)gr * H + c);
        *(float4*)(&zs[r][c]) = v;
    }
    __syncthreads();

    const int tx = tid & 31;
    const int ty = tid >> 5;
    const int c0 = tx << 2;
    const int r0 = ty << 2;

    float acc[4][4];
    #pragma unroll
    for (int i = 0; i < 4; ++i)
        #pragma unroll
        for (int j = 0; j < 4; ++j) acc[i][j] = 0.f;

    for (int k = 0; k < H; k += 4) {
        float zr[4][4];
        #pragma unroll
        for (int i = 0; i < 4; ++i)
            *(float4*)zr[i] = *(const float4*)(&zs[r0 + i][k]);
        float wr[4][4];
        const float* wp = w1 + (size_t)k * H + c0;
        #pragma unroll
        for (int kk = 0; kk < 4; ++kk)
            *(float4*)wr[kk] = *(const float4*)(wp + (size_t)kk * H);
        #pragma unroll
        for (int kk = 0; kk < 4; ++kk)
            #pragma unroll
            for (int i = 0; i < 4; ++i)
                #pragma unroll
                for (int j = 0; j < 4; ++j)
                    acc[i][j] += zr[i][kk] * wr[kk][j];
    }
    {
        float bb[4];
        *(float4*)bb = *(const float4*)(b1 + c0);
        #pragma unroll
        for (int i = 0; i < 4; ++i) {
            float4 o;
            o.x = fmaxf(acc[i][0] + bb[0], 0.f);
            o.y = fmaxf(acc[i][1] + bb[1], 0.f);
            o.z = fmaxf(acc[i][2] + bb[2], 0.f);
            o.w = fmaxf(acc[i][3] + bb[3], 0.f);
            *(float4*)(&ts[r0 + i][c0]) = o;
        }
    }
    __syncthreads();

    float acc2[4][4];
    #pragma unroll
    for (int i = 0; i < 4; ++i)
        #pragma unroll
        for (int j = 0; j < 4; ++j) acc2[i][j] = 0.f;

    for (int k = 0; k < H; k += 4) {
        float tr[4][4];
        #pragma unroll
        for (int i = 0; i < 4; ++i)
            *(float4*)tr[i] = *(const float4*)(&ts[r0 + i][k]);
        float wr[4][4];
        const float* wp = w2 + (size_t)k * H + c0;
        #pragma unroll
        for (int kk = 0; kk < 4; ++kk)
            *(float4*)wr[kk] = *(const float4*)(wp + (size_t)kk * H);
        #pragma unroll
        for (int kk = 0; kk < 4; ++kk)
            #pragma unroll
            for (int i = 0; i < 4; ++i)
                #pragma unroll
                for (int j = 0; j < 4; ++j)
                    acc2[i][j] += tr[i][kk] * wr[kk][j];
    }
    {
        float bb[4], gm[4], bt[4], mn[4], vr[4];
        *(float4*)bb = *(const float4*)(b2 + c0);
        *(float4*)gm = *(const float4*)(gamma + c0);
        *(float4*)bt = *(const float4*)(beta + c0);
        *(float4*)mn = *(const float4*)(mean + c0);
        *(float4*)vr = *(const float4*)(var + c0);
        float sc[4];
        #pragma unroll
        for (int j = 0; j < 4; ++j) sc[j] = gm[j] * rsqrtf(vr[j] + 1e-5f);
        #pragma unroll
        for (int i = 0; i < 4; ++i) {
            int gr = row0 + r0 + i;
            if (gr < n) {
                float4 o;
                o.x = fmaxf((acc2[i][0] + bb[0] - mn[0]) * sc[0] + bt[0], 0.f);
                o.y = fmaxf((acc2[i][1] + bb[1] - mn[1]) * sc[1] + bt[1], 0.f);
                o.z = fmaxf((acc2[i][2] + bb[2] - mn[2]) * sc[2] + bt[2], 0.f);
                o.w = fmaxf((acc2[i][3] + bb[3] - mn[3]) * sc[3] + bt[3], 0.f);
                *(float4*)(h + (size_t)gr * H + c0) = o;
            }
        }
    }
}

// ---- graph boundaries from sorted batch: gstart[g] = first node of graph g ----
__global__ void gbound_kernel(const int* __restrict__ batch, int* __restrict__ gstart, int n) {
    int i = blockIdx.x * blockDim.x + threadIdx.x;
    if (i >= n) return;
    int b = batch[i];
    if (i == 0) {
        for (int g = 0; g <= b; ++g) gstart[g] = 0;
    } else {
        int p = batch[i - 1];
        for (int g = p + 1; g <= b; ++g) gstart[g] = i;
    }
    if (i == n - 1) {
        for (int g = b + 1; g <= NGRAPH; ++g) gstart[g] = n;
    }
}

// ---- global mean pool: segmented gather, LDS reduce, few atomics ----
__global__ __launch_bounds__(256) void pool_kernel(const float* __restrict__ h,
                                                   const int* __restrict__ gstart,
                                                   float* __restrict__ sums) {
    __shared__ float4 buf[8][32];
    const int g = blockIdx.x;       // graph
    const int split = blockIdx.y;   // 0..7
    const int t = threadIdx.x;
    const int c32 = t & 31;
    const int c = c32 << 2;
    const int r = t >> 5;           // 0..7
    int s0 = gstart[g], s1 = gstart[g + 1];
    int len = s1 - s0;
    int chunk = (len + 7) >> 3;
    int a = s0 + split * chunk;
    int b = min(a + chunk, s1);
    float4 acc = make_float4(0.f, 0.f, 0.f, 0.f);
    for (int i = a + r; i < b; i += 8) {
        float4 v = *(const float4*)(h + (size_t)i * H + c);
        acc.x += v.x; acc.y += v.y; acc.z += v.z; acc.w += v.w;
    }
    buf[r][c32] = acc;
    __syncthreads();
    if (r == 0) {
        float4 s = buf[0][c32];
        #pragma unroll
        for (int k = 1; k < 8; ++k) {
            float4 v = buf[k][c32];
            s.x += v.x; s.y += v.y; s.z += v.z; s.w += v.w;
        }
        float* sp = sums + (size_t)g * H + c;
        atomicAdd(sp + 0, s.x);
        atomicAdd(sp + 1, s.y);
        atomicAdd(sp + 2, s.z);
        atomicAdd(sp + 3, s.w);
    }
}

// ---------------- classifier: sigmoid(relu(g@w1+b1)@w2+b2) ----------------
__global__ void cls_kernel(const float* __restrict__ sums, const int* __restrict__ gstart,
                           const float* __restrict__ w1, const float* __restrict__ b1,
                           const float* __restrict__ w2, const float* __restrict__ b2,
                           float* __restrict__ out) {
    int g = blockIdx.x;     // 64 graphs
    int m = threadIdx.x;    // 64 mids
    float cnt = (float)(gstart[g + 1] - gstart[g]);
    float inv = 1.0f / fmaxf(cnt, 1.0f);
    float acc = 0.f;
    for (int k = 0; k < H; ++k) {
        float gk = sums[(size_t)g * H + k] * inv;
        acc += gk * w1[(size_t)k * 64 + m];
    }
    float tm = fmaxf(acc + b1[m], 0.f);
    float p = tm * w2[m];
    #pragma unroll
    for (int off = 32; off > 0; off >>= 1) p += __shfl_down(p, off, 64);
    if (m == 0) out[g] = 1.f / (1.f + expf(-(p + b2[0])));
}

extern "C" void kernel_launch(void* const* d_in, const int* in_sizes, int n_in,
                              void* d_out, int out_size, void* d_ws, size_t ws_size,
                              hipStream_t stream) {
    const float* x      = (const float*)d_in[0];
    const int*   ei     = (const int*)d_in[1];
    const float* ea     = (const float*)d_in[2];
    const int*   batch  = (const int*)d_in[3];
    const float* enc_w  = (const float*)d_in[4];
    const float* enc_b  = (const float*)d_in[5];
    const float* edge_w = (const float*)d_in[6];
    const float* edge_b = (const float*)d_in[7];
    const float* eps    = (const float*)d_in[8];
    const float* mlp_w1 = (const float*)d_in[9];
    const float* mlp_b1 = (const float*)d_in[10];
    const float* mlp_w2 = (const float*)d_in[11];
    const float* mlp_b2 = (const float*)d_in[12];
    const float* bn_g   = (const float*)d_in[13];
    const float* bn_b   = (const float*)d_in[14];
    const float* bn_m   = (const float*)d_in[15];
    const float* bn_v   = (const float*)d_in[16];
    const float* cls_w1 = (const float*)d_in[17];
    const float* cls_b1 = (const float*)d_in[18];
    const float* cls_w2 = (const float*)d_in[19];
    const float* cls_b2 = (const float*)d_in[20];
    float* out = (float*)d_out;

    const int n = in_sizes[0];        // 100000
    const int ne = in_sizes[2];       // 1600000
    const int nb = (n + 1023) / 1024; // scan blocks

    // workspace layout (all regions 16B-aligned)
    float* h      = (float*)d_ws;                       // N*H
    float* z      = h + (size_t)n * H;                  // N*H
    float* sums   = z + (size_t)n * H;                  // G*H
    int*   gstart = (int*)(sums + (size_t)NGRAPH * H);  // G+4
    int*   deg    = gstart + NGRAPH + 4;                // N
    int*   start  = deg + n;                            // N+4
    int*   cursor = start + n + 4;                      // N
    int*   bsum   = cursor + n;                         // 256
    int*   bscan  = bsum + 256;                         // 256
    int2*  sedge  = (int2*)(bscan + 256);               // E

    hipMemsetAsync(sums, 0, (size_t)NGRAPH * H * sizeof(float), stream);
    hipMemsetAsync(deg, 0, (size_t)n * sizeof(int), stream);
    hipMemsetAsync(cursor, 0, (size_t)n * sizeof(int), stream);

    // ---- counting sort of edges by dst (once; reused both layers) ----
    hist_kernel<<<(ne + 255) / 256, 256, 0, stream>>>(ei, deg, ne);
    scan1_kernel<<<nb, 256, 0, stream>>>(deg, start, bsum, n);
    scan2_kernel<<<1, 256, 0, stream>>>(bsum, bscan, start, nb, n);
    scan3_kernel<<<(n + 255) / 256, 256, 0, stream>>>(start, bscan, n);
    scatter_kernel<<<(ne + 255) / 256, 256, 0, stream>>>(ei, ea, start, cursor, sedge, ne);

    // graph boundaries for pooling
    gbound_kernel<<<(n + 255) / 256, 256, 0, stream>>>(batch, gstart, n);

    // encoder
    {
        int threads = n * 32;
        enc_kernel<<<(threads + 255) / 256, 256, 0, stream>>>(x, enc_w, enc_b, h, n);
    }

    for (int l = 0; l < NLAYERS; ++l) {
        {
            int threads = n * 64;
            aggregate_kernel<<<(threads + 255) / 256, 256, 0, stream>>>(
                h, start, sedge, edge_w, edge_b, eps, l, z, n);
        }
        mlp_kernel<<<(n + TM - 1) / TM, 256, 0, stream>>>(
            h, z,
            mlp_w1 + (size_t)l * H * H, mlp_b1 + (size_t)l * H,
            mlp_w2 + (size_t)l * H * H, mlp_b2 + (size_t)l * H,
            bn_g + (size_t)l * H, bn_b + (size_t)l * H,
            bn_m + (size_t)l * H, bn_v + (size_t)l * H, n);
    }

    pool_kernel<<<dim3(NGRAPH, 8), 256, 0, stream>>>(h, gstart, sums);
    cls_kernel<<<NGRAPH, 64, 0, stream>>>(sums, gstart, cls_w1, cls_b1, cls_w2, cls_b2, out);
}

// Round 4
// 671.816 us; speedup vs baseline: 9.8168x; 1.0938x over previous
//
#include <hip/hip_runtime.h>
#include <hip/hip_bf16.h>

#define H 128
#define NGRAPH 64
#define NLAYERS 2
#define TMM 64          // rows per MLP block
#define TP 136          // t-tile LDS row stride in bf16 (pad 8)

typedef short short8 __attribute__((ext_vector_type(8)));
typedef float floatx4 __attribute__((ext_vector_type(4)));

// ---------------- encoder: h[i][j] = x[i]*enc_w[j] + enc_b[j] ----------------
__global__ void enc_kernel(const float* __restrict__ x, const float* __restrict__ w,
                           const float* __restrict__ b, float* __restrict__ h, int n) {
    int t = blockIdx.x * blockDim.x + threadIdx.x;
    int i = t >> 5;            // node
    int c = (t & 31) << 2;     // feature*4
    if (i >= n) return;
    float xv = x[i];
    float4 wv = *(const float4*)(w + c);
    float4 bv = *(const float4*)(b + c);
    float4 o;
    o.x = xv * wv.x + bv.x;
    o.y = xv * wv.y + bv.y;
    o.z = xv * wv.z + bv.z;
    o.w = xv * wv.w + bv.w;
    *(float4*)(h + (size_t)i * H + c) = o;
}

// ------- prep: cast+transpose mlp weights to bf16 [l][n][k] -------
__global__ void prep_kernel(const float* __restrict__ w1, const float* __restrict__ w2,
                            unsigned short* __restrict__ w1t, unsigned short* __restrict__ w2t) {
    int idx = blockIdx.x * blockDim.x + threadIdx.x;   // 2*128*128
    int l = idx >> 14;
    int r = idx & 16383;
    int nn = r >> 7;
    int kk = r & 127;
    __hip_bfloat16 a = __float2bfloat16(w1[(size_t)l * 16384 + kk * 128 + nn]);
    __hip_bfloat16 b = __float2bfloat16(w2[(size_t)l * 16384 + kk * 128 + nn]);
    w1t[(size_t)l * 16384 + nn * 128 + kk] = *(unsigned short*)&a;
    w2t[(size_t)l * 16384 + nn * 128 + kk] = *(unsigned short*)&b;
}

// ---------------- counting-sort by dst: histogram ----------------
__global__ void hist_kernel(const int* __restrict__ ei, int* __restrict__ deg, int ne) {
    int e = blockIdx.x * blockDim.x + threadIdx.x;
    if (e >= ne) return;
    atomicAdd(&deg[ei[ne + e]], 1);
}

// -------- hierarchical exclusive scan, level 1: 1024 elems per block --------
__global__ __launch_bounds__(256) void scan1_kernel(const int* __restrict__ deg,
                                                    int* __restrict__ start,
                                                    int* __restrict__ bsum, int n) {
    __shared__ int wsum[4];
    const int t = threadIdx.x;
    const int lane = t & 63;
    const int wid = t >> 6;
    const int base = blockIdx.x * 1024 + t * 4;
    int4 v = make_int4(0, 0, 0, 0);
    if (base + 3 < n) v = *(const int4*)(deg + base);
    else {
        if (base + 0 < n) v.x = deg[base + 0];
        if (base + 1 < n) v.y = deg[base + 1];
        if (base + 2 < n) v.z = deg[base + 2];
    }
    int s = v.x + v.y + v.z + v.w;
    int incl = s;
    #pragma unroll
    for (int off = 1; off < 64; off <<= 1) {
        int u = __shfl_up(incl, off, 64);
        if (lane >= off) incl += u;
    }
    if (lane == 63) wsum[wid] = incl;
    __syncthreads();
    int woff = 0;
    #pragma unroll
    for (int k = 0; k < 4; ++k) if (k < wid) woff += wsum[k];
    int excl = woff + incl - s;
    int4 o;
    o.x = excl;
    o.y = o.x + v.x;
    o.z = o.y + v.y;
    o.w = o.z + v.z;
    if (base + 3 < n) *(int4*)(start + base) = o;
    else {
        if (base + 0 < n) start[base + 0] = o.x;
        if (base + 1 < n) start[base + 1] = o.y;
        if (base + 2 < n) start[base + 2] = o.z;
    }
    if (t == 255) bsum[blockIdx.x] = woff + incl;
}

// -------- scan level 2: scan block sums (nb <= 256), write total to start[n] --
__global__ __launch_bounds__(256) void scan2_kernel(const int* __restrict__ bsum,
                                                    int* __restrict__ bscan,
                                                    int* __restrict__ start, int nb, int n) {
    __shared__ int wsum[4];
    const int t = threadIdx.x;
    const int lane = t & 63;
    const int wid = t >> 6;
    int v = (t < nb) ? bsum[t] : 0;
    int incl = v;
    #pragma unroll
    for (int off = 1; off < 64; off <<= 1) {
        int u = __shfl_up(incl, off, 64);
        if (lane >= off) incl += u;
    }
    if (lane == 63) wsum[wid] = incl;
    __syncthreads();
    int woff = 0;
    #pragma unroll
    for (int k = 0; k < 4; ++k) if (k < wid) woff += wsum[k];
    if (t < nb) bscan[t] = woff + incl - v;
    if (t == 255) start[n] = woff + incl;
}

// -------- scan level 3: add block offsets --------
__global__ void scan3_kernel(int* __restrict__ start, const int* __restrict__ bscan, int n) {
    int i = blockIdx.x * blockDim.x + threadIdx.x;
    if (i < n) start[i] += bscan[i >> 10];
}

// ------- counting-sort: scatter (src, attr) packed into dst order -------
__global__ void scatter_kernel(const int* __restrict__ ei, const float* __restrict__ ea,
                               const int* __restrict__ start, int* __restrict__ cursor,
                               int2* __restrict__ sedge, int ne) {
    int e = blockIdx.x * blockDim.x + threadIdx.x;
    if (e >= ne) return;
    int dst = ei[ne + e];
    int pos = start[dst] + atomicAdd(&cursor[dst], 1);
    int2 p;
    p.x = ei[e];
    p.y = __float_as_int(ea[e]);
    sedge[pos] = p;
}

// ---- segment-reduce gather: z[i] = (1+eps)*h[i] + sum_j relu(h[src_j]+e_j) ----
// one wave per node, float2 per lane, 8-way unrolled; writes z in bf16
__global__ __launch_bounds__(256) void aggregate_kernel(
    const float* __restrict__ h, const int* __restrict__ start,
    const int2* __restrict__ sedge,
    const float* __restrict__ ew, const float* __restrict__ eb,
    const float* __restrict__ epsp, int layer,
    unsigned short* __restrict__ z, int n) {
    int node = (blockIdx.x * blockDim.x + threadIdx.x) >> 6;
    int lane = threadIdx.x & 63;
    if (node >= n) return;
    int c = lane << 1;
    float2 wv = *(const float2*)(ew + c);
    float2 bv = *(const float2*)(eb + c);
    float2 acc = make_float2(0.f, 0.f);
    int s0 = start[node], s1 = start[node + 1];
    int j = s0;
    for (; j + 8 <= s1; j += 8) {
        int2 e[8];
        float2 hv[8];
        #pragma unroll
        for (int k = 0; k < 8; ++k) e[k] = sedge[j + k];
        #pragma unroll
        for (int k = 0; k < 8; ++k)
            hv[k] = *(const float2*)(h + (size_t)e[k].x * H + c);
        #pragma unroll
        for (int k = 0; k < 8; ++k) {
            float a = __int_as_float(e[k].y);
            acc.x += fmaxf(fmaf(a, wv.x, bv.x) + hv[k].x, 0.f);
            acc.y += fmaxf(fmaf(a, wv.y, bv.y) + hv[k].y, 0.f);
        }
    }
    for (; j < s1; ++j) {
        int2 e = sedge[j];
        float a = __int_as_float(e.y);
        float2 hv = *(const float2*)(h + (size_t)e.x * H + c);
        acc.x += fmaxf(fmaf(a, wv.x, bv.x) + hv.x, 0.f);
        acc.y += fmaxf(fmaf(a, wv.y, bv.y) + hv.y, 0.f);
    }
    float ev = 1.0f + epsp[layer];
    float2 hv = *(const float2*)(h + (size_t)node * H + c);
    __hip_bfloat16 ox = __float2bfloat16(fmaf(ev, hv.x, acc.x));
    __hip_bfloat16 oy = __float2bfloat16(fmaf(ev, hv.y, acc.y));
    ushort2 p = make_ushort2(*(unsigned short*)&ox, *(unsigned short*)&oy);
    *(ushort2*)(z + (size_t)node * H + c) = p;
}

// ---- MFMA node MLP: h = relu(BN(relu(z@w1+b1)@w2+b2)), bf16 in / f32 out ----
// 64 rows/block, 4 waves x 16 rows; per-wave t-tile in LDS (no barriers needed)
__global__ __launch_bounds__(256) void mfma_mlp_kernel(
    float* __restrict__ h, const unsigned short* __restrict__ z,
    const unsigned short* __restrict__ w1t, const float* __restrict__ b1,
    const unsigned short* __restrict__ w2t, const float* __restrict__ b2,
    const float* __restrict__ gamma, const float* __restrict__ beta,
    const float* __restrict__ mean, const float* __restrict__ var, int n) {
    __shared__ unsigned short ts[TMM * TP];
    const int tid = threadIdx.x;
    const int wid = tid >> 6;
    const int lane = tid & 63;
    const int m = lane & 15;     // A row within 16 / B col
    const int q = lane >> 4;     // quad
    const int row0 = blockIdx.x * TMM + wid * 16;

    // ---------- GEMM1: t = relu(z @ w1 + b1) ----------
    floatx4 acc[8];
    #pragma unroll
    for (int ct = 0; ct < 8; ++ct) acc[ct] = (floatx4)(0.f);

    const unsigned short* zrow = z + (size_t)(row0 + m) * H + q * 8;
    #pragma unroll
    for (int kb = 0; kb < H; kb += 32) {
        short8 a = *(const short8*)(zrow + kb);
        #pragma unroll
        for (int ct = 0; ct < 8; ++ct) {
            short8 b = *(const short8*)(w1t + (size_t)(ct * 16 + m) * H + kb + q * 8);
            acc[ct] = __builtin_amdgcn_mfma_f32_16x16x32_bf16(a, b, acc[ct], 0, 0, 0);
        }
    }
    // epilogue 1: +bias, relu, cast bf16 -> per-wave t tile in LDS
    unsigned short* tw = ts + wid * 16 * TP;
    #pragma unroll
    for (int ct = 0; ct < 8; ++ct) {
        float bb = b1[ct * 16 + m];
        #pragma unroll
        for (int r = 0; r < 4; ++r) {
            float v = fmaxf(acc[ct][r] + bb, 0.f);
            __hip_bfloat16 bv = __float2bfloat16(v);
            tw[(q * 4 + r) * TP + ct * 16 + m] = *(unsigned short*)&bv;
        }
    }

    // ---------- GEMM2: z2 = t @ w2 + b2, then BN + relu ----------
    floatx4 acc2[8];
    #pragma unroll
    for (int ct = 0; ct < 8; ++ct) acc2[ct] = (floatx4)(0.f);

    const unsigned short* trow = tw + m * TP + q * 8;
    #pragma unroll
    for (int kb = 0; kb < H; kb += 32) {
        short8 a = *(const short8*)(trow + kb);
        #pragma unroll
        for (int ct = 0; ct < 8; ++ct) {
            short8 b = *(const short8*)(w2t + (size_t)(ct * 16 + m) * H + kb + q * 8);
            acc2[ct] = __builtin_amdgcn_mfma_f32_16x16x32_bf16(a, b, acc2[ct], 0, 0, 0);
        }
    }
    #pragma unroll
    for (int ct = 0; ct < 8; ++ct) {
        int col = ct * 16 + m;
        float bb = b2[col];
        float sc = gamma[col] * rsqrtf(var[col] + 1e-5f);
        float mn = mean[col];
        float bt = beta[col];
        #pragma unroll
        for (int r = 0; r < 4; ++r) {
            int grow = row0 + q * 4 + r;
            if (grow < n) {
                float v = fmaxf((acc2[ct][r] + bb - mn) * sc + bt, 0.f);
                h[(size_t)grow * H + col] = v;
            }
        }
    }
}

// ---- graph boundaries from sorted batch: gstart[g] = first node of graph g ----
__global__ void gbound_kernel(const int* __restrict__ batch, int* __restrict__ gstart, int n) {
    int i = blockIdx.x * blockDim.x + threadIdx.x;
    if (i >= n) return;
    int b = batch[i];
    if (i == 0) {
        for (int g = 0; g <= b; ++g) gstart[g] = 0;
    } else {
        int p = batch[i - 1];
        for (int g = p + 1; g <= b; ++g) gstart[g] = i;
    }
    if (i == n - 1) {
        for (int g = b + 1; g <= NGRAPH; ++g) gstart[g] = n;
    }
}

// ---- global mean pool: segmented gather, LDS reduce, few atomics ----
__global__ __launch_bounds__(256) void pool_kernel(const float* __restrict__ h,
                                                   const int* __restrict__ gstart,
                                                   float* __restrict__ sums) {
    __shared__ float4 buf[8][32];
    const int g = blockIdx.x;       // graph
    const int split = blockIdx.y;   // 0..7
    const int t = threadIdx.x;
    const int c32 = t & 31;
    const int c = c32 << 2;
    const int r = t >> 5;           // 0..7
    int s0 = gstart[g], s1 = gstart[g + 1];
    int len = s1 - s0;
    int chunk = (len + 7) >> 3;
    int a = s0 + split * chunk;
    int b = min(a + chunk, s1);
    float4 acc = make_float4(0.f, 0.f, 0.f, 0.f);
    for (int i = a + r; i < b; i += 8) {
        float4 v = *(const float4*)(h + (size_t)i * H + c);
        acc.x += v.x; acc.y += v.y; acc.z += v.z; acc.w += v.w;
    }
    buf[r][c32] = acc;
    __syncthreads();
    if (r == 0) {
        float4 s = buf[0][c32];
        #pragma unroll
        for (int k = 1; k < 8; ++k) {
            float4 v = buf[k][c32];
            s.x += v.x; s.y += v.y; s.z += v.z; s.w += v.w;
        }
        float* sp = sums + (size_t)g * H + c;
        atomicAdd(sp + 0, s.x);
        atomicAdd(sp + 1, s.y);
        atomicAdd(sp + 2, s.z);
        atomicAdd(sp + 3, s.w);
    }
}

// ---------------- classifier: sigmoid(relu(g@w1+b1)@w2+b2) ----------------
__global__ void cls_kernel(const float* __restrict__ sums, const int* __restrict__ gstart,
                           const float* __restrict__ w1, const float* __restrict__ b1,
                           const float* __restrict__ w2, const float* __restrict__ b2,
                           float* __restrict__ out) {
    int g = blockIdx.x;     // 64 graphs
    int m = threadIdx.x;    // 64 mids
    float cnt = (float)(gstart[g + 1] - gstart[g]);
    float inv = 1.0f / fmaxf(cnt, 1.0f);
    float acc = 0.f;
    for (int k = 0; k < H; ++k) {
        float gk = sums[(size_t)g * H + k] * inv;
        acc += gk * w1[(size_t)k * 64 + m];
    }
    float tm = fmaxf(acc + b1[m], 0.f);
    float p = tm * w2[m];
    #pragma unroll
    for (int off = 32; off > 0; off >>= 1) p += __shfl_down(p, off, 64);
    if (m == 0) out[g] = 1.f / (1.f + expf(-(p + b2[0])));
}

extern "C" void kernel_launch(void* const* d_in, const int* in_sizes, int n_in,
                              void* d_out, int out_size, void* d_ws, size_t ws_size,
                              hipStream_t stream) {
    const float* x      = (const float*)d_in[0];
    const int*   ei     = (const int*)d_in[1];
    const float* ea     = (const float*)d_in[2];
    const int*   batch  = (const int*)d_in[3];
    const float* enc_w  = (const float*)d_in[4];
    const float* enc_b  = (const float*)d_in[5];
    const float* edge_w = (const float*)d_in[6];
    const float* edge_b = (const float*)d_in[7];
    const float* eps    = (const float*)d_in[8];
    const float* mlp_w1 = (const float*)d_in[9];
    const float* mlp_b1 = (const float*)d_in[10];
    const float* mlp_w2 = (const float*)d_in[11];
    const float* mlp_b2 = (const float*)d_in[12];
    const float* bn_g   = (const float*)d_in[13];
    const float* bn_b   = (const float*)d_in[14];
    const float* bn_m   = (const float*)d_in[15];
    const float* bn_v   = (const float*)d_in[16];
    const float* cls_w1 = (const float*)d_in[17];
    const float* cls_b1 = (const float*)d_in[18];
    const float* cls_w2 = (const float*)d_in[19];
    const float* cls_b2 = (const float*)d_in[20];
    float* out = (float*)d_out;

    const int n = in_sizes[0];        // 100000
    const int ne = in_sizes[2];       // 1600000
    const int nb = (n + 1023) / 1024; // scan blocks

    // workspace layout (regions kept 16B-aligned)
    float* h            = (float*)d_ws;                             // N*H f32
    unsigned short* zb  = (unsigned short*)(h + (size_t)n * H);     // N*H bf16
    float* sums         = (float*)(zb + (size_t)n * H);             // G*H
    int*   gstart       = (int*)(sums + (size_t)NGRAPH * H);        // G+4
    int*   deg          = gstart + NGRAPH + 4;                      // N
    int*   start        = deg + n;                                  // N+4
    int*   cursor       = start + n + 4;                            // N
    int*   bsum         = cursor + n;                               // 256
    int*   bscan        = bsum + 256;                               // 256
    unsigned short* w1t = (unsigned short*)(bscan + 256);           // 2*128*128
    unsigned short* w2t = w1t + 2 * 16384;                          // 2*128*128
    int2*  sedge        = (int2*)(w2t + 2 * 16384);                 // E

    hipMemsetAsync(sums, 0, (size_t)NGRAPH * H * sizeof(float), stream);
    hipMemsetAsync(deg, 0, (size_t)n * sizeof(int), stream);
    hipMemsetAsync(cursor, 0, (size_t)n * sizeof(int), stream);

    // weight prep (bf16 transpose) — once per call
    prep_kernel<<<128, 256, 0, stream>>>(mlp_w1, mlp_w2, w1t, w2t);

    // ---- counting sort of edges by dst (once; reused both layers) ----
    hist_kernel<<<(ne + 255) / 256, 256, 0, stream>>>(ei, deg, ne);
    scan1_kernel<<<nb, 256, 0, stream>>>(deg, start, bsum, n);
    scan2_kernel<<<1, 256, 0, stream>>>(bsum, bscan, start, nb, n);
    scan3_kernel<<<(n + 255) / 256, 256, 0, stream>>>(start, bscan, n);
    scatter_kernel<<<(ne + 255) / 256, 256, 0, stream>>>(ei, ea, start, cursor, sedge, ne);

    // graph boundaries for pooling
    gbound_kernel<<<(n + 255) / 256, 256, 0, stream>>>(batch, gstart, n);

    // encoder
    {
        int threads = n * 32;
        enc_kernel<<<(threads + 255) / 256, 256, 0, stream>>>(x, enc_w, enc_b, h, n);
    }

    for (int l = 0; l < NLAYERS; ++l) {
        {
            int threads = n * 64;
            aggregate_kernel<<<(threads + 255) / 256, 256, 0, stream>>>(
                h, start, sedge, edge_w, edge_b, eps, l, zb, n);
        }
        mfma_mlp_kernel<<<(n + TMM - 1) / TMM, 256, 0, stream>>>(
            h, zb,
            w1t + (size_t)l * 16384, mlp_b1 + (size_t)l * H,
            w2t + (size_t)l * 16384, mlp_b2 + (size_t)l * H,
            bn_g + (size_t)l * H, bn_b + (size_t)l * H,
            bn_m + (size_t)l * H, bn_v + (size_t)l * H, n);
    }

    pool_kernel<<<dim3(NGRAPH, 8), 256, 0, stream>>>(h, gstart, sums);
    cls_kernel<<<NGRAPH, 64, 0, stream>>>(sums, gstart, cls_w1, cls_b1, cls_w2, cls_b2, out);
}

// Round 5
// 580.780 us; speedup vs baseline: 11.3555x; 1.1567x over previous
//
#include <hip/hip_runtime.h>
#include <hip/hip_bf16.h>

#define H 128
#define NGRAPH 64
#define NLAYERS 2
#define TMM 64          // rows per MLP block
#define TP 136          // t-tile LDS row stride in bf16 (pad 8)

typedef short short8 __attribute__((ext_vector_type(8)));
typedef float floatx4 __attribute__((ext_vector_type(4)));

static __device__ __forceinline__ unsigned short f2bf(float v) {
    __hip_bfloat16 b = __float2bfloat16(v);
    return *(unsigned short*)&b;
}
static __device__ __forceinline__ float bf2f(unsigned short u) {
    return __uint_as_float(((unsigned int)u) << 16);
}

// ---------------- encoder: h[i][j] = bf16(x[i]*enc_w[j] + enc_b[j]) ----------------
__global__ void enc_kernel(const float* __restrict__ x, const float* __restrict__ w,
                           const float* __restrict__ b, unsigned short* __restrict__ h, int n) {
    int t = blockIdx.x * blockDim.x + threadIdx.x;
    int i = t >> 5;            // node
    int c = (t & 31) << 2;     // feature*4
    if (i >= n) return;
    float xv = x[i];
    float4 wv = *(const float4*)(w + c);
    float4 bv = *(const float4*)(b + c);
    ushort4 o;
    o.x = f2bf(xv * wv.x + bv.x);
    o.y = f2bf(xv * wv.y + bv.y);
    o.z = f2bf(xv * wv.z + bv.z);
    o.w = f2bf(xv * wv.w + bv.w);
    *(ushort4*)(h + (size_t)i * H + c) = o;
}

// ------- prep: cast+transpose mlp weights to bf16 [l][n][k] -------
__global__ void prep_kernel(const float* __restrict__ w1, const float* __restrict__ w2,
                            unsigned short* __restrict__ w1t, unsigned short* __restrict__ w2t) {
    int idx = blockIdx.x * blockDim.x + threadIdx.x;   // 2*128*128
    int l = idx >> 14;
    int r = idx & 16383;
    int nn = r >> 7;
    int kk = r & 127;
    w1t[(size_t)l * 16384 + nn * 128 + kk] = f2bf(w1[(size_t)l * 16384 + kk * 128 + nn]);
    w2t[(size_t)l * 16384 + nn * 128 + kk] = f2bf(w2[(size_t)l * 16384 + kk * 128 + nn]);
}

// ---------------- counting-sort by dst: histogram ----------------
__global__ void hist_kernel(const int* __restrict__ ei, int* __restrict__ deg, int ne) {
    int e = blockIdx.x * blockDim.x + threadIdx.x;
    if (e >= ne) return;
    atomicAdd(&deg[ei[ne + e]], 1);
}

// -------- hierarchical exclusive scan, level 1: 1024 elems per block --------
__global__ __launch_bounds__(256) void scan1_kernel(const int* __restrict__ deg,
                                                    int* __restrict__ start,
                                                    int* __restrict__ bsum, int n) {
    __shared__ int wsum[4];
    const int t = threadIdx.x;
    const int lane = t & 63;
    const int wid = t >> 6;
    const int base = blockIdx.x * 1024 + t * 4;
    int4 v = make_int4(0, 0, 0, 0);
    if (base + 3 < n) v = *(const int4*)(deg + base);
    else {
        if (base + 0 < n) v.x = deg[base + 0];
        if (base + 1 < n) v.y = deg[base + 1];
        if (base + 2 < n) v.z = deg[base + 2];
    }
    int s = v.x + v.y + v.z + v.w;
    int incl = s;
    #pragma unroll
    for (int off = 1; off < 64; off <<= 1) {
        int u = __shfl_up(incl, off, 64);
        if (lane >= off) incl += u;
    }
    if (lane == 63) wsum[wid] = incl;
    __syncthreads();
    int woff = 0;
    #pragma unroll
    for (int k = 0; k < 4; ++k) if (k < wid) woff += wsum[k];
    int excl = woff + incl - s;
    int4 o;
    o.x = excl;
    o.y = o.x + v.x;
    o.z = o.y + v.y;
    o.w = o.z + v.z;
    if (base + 3 < n) *(int4*)(start + base) = o;
    else {
        if (base + 0 < n) start[base + 0] = o.x;
        if (base + 1 < n) start[base + 1] = o.y;
        if (base + 2 < n) start[base + 2] = o.z;
    }
    if (t == 255) bsum[blockIdx.x] = woff + incl;
}

// -------- scan level 2: scan block sums (nb <= 256), write total to start[n] --
__global__ __launch_bounds__(256) void scan2_kernel(const int* __restrict__ bsum,
                                                    int* __restrict__ bscan,
                                                    int* __restrict__ start, int nb, int n) {
    __shared__ int wsum[4];
    const int t = threadIdx.x;
    const int lane = t & 63;
    const int wid = t >> 6;
    int v = (t < nb) ? bsum[t] : 0;
    int incl = v;
    #pragma unroll
    for (int off = 1; off < 64; off <<= 1) {
        int u = __shfl_up(incl, off, 64);
        if (lane >= off) incl += u;
    }
    if (lane == 63) wsum[wid] = incl;
    __syncthreads();
    int woff = 0;
    #pragma unroll
    for (int k = 0; k < 4; ++k) if (k < wid) woff += wsum[k];
    if (t < nb) bscan[t] = woff + incl - v;
    if (t == 255) start[n] = woff + incl;
}

// -------- scan level 3: add block offsets --------
__global__ void scan3_kernel(int* __restrict__ start, const int* __restrict__ bscan, int n) {
    int i = blockIdx.x * blockDim.x + threadIdx.x;
    if (i < n) start[i] += bscan[i >> 10];
}

// ------- counting-sort: scatter (src, attr) packed into dst order -------
__global__ void scatter_kernel(const int* __restrict__ ei, const float* __restrict__ ea,
                               const int* __restrict__ start, int* __restrict__ cursor,
                               int2* __restrict__ sedge, int ne) {
    int e = blockIdx.x * blockDim.x + threadIdx.x;
    if (e >= ne) return;
    int dst = ei[ne + e];
    int pos = start[dst] + atomicAdd(&cursor[dst], 1);
    int2 p;
    p.x = ei[e];
    p.y = __float_as_int(ea[e]);
    sedge[pos] = p;
}

// ---- segment-reduce gather: z[i] = (1+eps)*h[i] + sum_j relu(h[src_j]+e_j) ----
// one wave per node, bf16 h rows (256 B/row gather), f32 accumulate, bf16 z out
__global__ __launch_bounds__(256) void aggregate_kernel(
    const unsigned short* __restrict__ h, const int* __restrict__ start,
    const int2* __restrict__ sedge,
    const float* __restrict__ ew, const float* __restrict__ eb,
    const float* __restrict__ epsp, int layer,
    unsigned short* __restrict__ z, int n) {
    int node = (blockIdx.x * blockDim.x + threadIdx.x) >> 6;
    int lane = threadIdx.x & 63;
    if (node >= n) return;
    int c = lane << 1;
    float2 wv = *(const float2*)(ew + c);
    float2 bv = *(const float2*)(eb + c);
    float2 acc = make_float2(0.f, 0.f);
    int s0 = start[node], s1 = start[node + 1];
    int j = s0;
    for (; j + 8 <= s1; j += 8) {
        int2 e[8];
        ushort2 hv[8];
        #pragma unroll
        for (int k = 0; k < 8; ++k) e[k] = sedge[j + k];
        #pragma unroll
        for (int k = 0; k < 8; ++k)
            hv[k] = *(const ushort2*)(h + (size_t)e[k].x * H + c);
        #pragma unroll
        for (int k = 0; k < 8; ++k) {
            float a = __int_as_float(e[k].y);
            acc.x += fmaxf(fmaf(a, wv.x, bv.x) + bf2f(hv[k].x), 0.f);
            acc.y += fmaxf(fmaf(a, wv.y, bv.y) + bf2f(hv[k].y), 0.f);
        }
    }
    for (; j < s1; ++j) {
        int2 e = sedge[j];
        float a = __int_as_float(e.y);
        ushort2 hv = *(const ushort2*)(h + (size_t)e.x * H + c);
        acc.x += fmaxf(fmaf(a, wv.x, bv.x) + bf2f(hv.x), 0.f);
        acc.y += fmaxf(fmaf(a, wv.y, bv.y) + bf2f(hv.y), 0.f);
    }
    float ev = 1.0f + epsp[layer];
    ushort2 hv = *(const ushort2*)(h + (size_t)node * H + c);
    ushort2 p;
    p.x = f2bf(fmaf(ev, bf2f(hv.x), acc.x));
    p.y = f2bf(fmaf(ev, bf2f(hv.y), acc.y));
    *(ushort2*)(z + (size_t)node * H + c) = p;
}

// ---- MFMA node MLP: h = bf16(relu(BN(relu(z@w1+b1)@w2+b2))), bf16 in/out ----
// 64 rows/block, 4 waves x 16 rows; per-wave t-tile in LDS (no barriers needed)
__global__ __launch_bounds__(256) void mfma_mlp_kernel(
    unsigned short* __restrict__ h, const unsigned short* __restrict__ z,
    const unsigned short* __restrict__ w1t, const float* __restrict__ b1,
    const unsigned short* __restrict__ w2t, const float* __restrict__ b2,
    const float* __restrict__ gamma, const float* __restrict__ beta,
    const float* __restrict__ mean, const float* __restrict__ var, int n) {
    __shared__ unsigned short ts[TMM * TP];
    const int tid = threadIdx.x;
    const int wid = tid >> 6;
    const int lane = tid & 63;
    const int m = lane & 15;     // A row within 16 / B col
    const int q = lane >> 4;     // quad
    const int row0 = blockIdx.x * TMM + wid * 16;

    // ---------- GEMM1: t = relu(z @ w1 + b1) ----------
    floatx4 acc[8];
    #pragma unroll
    for (int ct = 0; ct < 8; ++ct) acc[ct] = (floatx4)(0.f);

    const unsigned short* zrow = z + (size_t)(row0 + m) * H + q * 8;
    #pragma unroll
    for (int kb = 0; kb < H; kb += 32) {
        short8 a = *(const short8*)(zrow + kb);
        #pragma unroll
        for (int ct = 0; ct < 8; ++ct) {
            short8 b = *(const short8*)(w1t + (size_t)(ct * 16 + m) * H + kb + q * 8);
            acc[ct] = __builtin_amdgcn_mfma_f32_16x16x32_bf16(a, b, acc[ct], 0, 0, 0);
        }
    }
    // epilogue 1: +bias, relu, cast bf16 -> per-wave t tile in LDS
    unsigned short* tw = ts + wid * 16 * TP;
    #pragma unroll
    for (int ct = 0; ct < 8; ++ct) {
        float bb = b1[ct * 16 + m];
        #pragma unroll
        for (int r = 0; r < 4; ++r) {
            float v = fmaxf(acc[ct][r] + bb, 0.f);
            tw[(q * 4 + r) * TP + ct * 16 + m] = f2bf(v);
        }
    }

    // ---------- GEMM2: z2 = t @ w2 + b2, then BN + relu ----------
    floatx4 acc2[8];
    #pragma unroll
    for (int ct = 0; ct < 8; ++ct) acc2[ct] = (floatx4)(0.f);

    const unsigned short* trow = tw + m * TP + q * 8;
    #pragma unroll
    for (int kb = 0; kb < H; kb += 32) {
        short8 a = *(const short8*)(trow + kb);
        #pragma unroll
        for (int ct = 0; ct < 8; ++ct) {
            short8 b = *(const short8*)(w2t + (size_t)(ct * 16 + m) * H + kb + q * 8);
            acc2[ct] = __builtin_amdgcn_mfma_f32_16x16x32_bf16(a, b, acc2[ct], 0, 0, 0);
        }
    }
    #pragma unroll
    for (int ct = 0; ct < 8; ++ct) {
        int col = ct * 16 + m;
        float bb = b2[col];
        float sc = gamma[col] * rsqrtf(var[col] + 1e-5f);
        float mn = mean[col];
        float bt = beta[col];
        #pragma unroll
        for (int r = 0; r < 4; ++r) {
            int grow = row0 + q * 4 + r;
            if (grow < n) {
                float v = fmaxf((acc2[ct][r] + bb - mn) * sc + bt, 0.f);
                h[(size_t)grow * H + col] = f2bf(v);
            }
        }
    }
}

// ---- graph boundaries from sorted batch: gstart[g] = first node of graph g ----
__global__ void gbound_kernel(const int* __restrict__ batch, int* __restrict__ gstart, int n) {
    int i = blockIdx.x * blockDim.x + threadIdx.x;
    if (i >= n) return;
    int b = batch[i];
    if (i == 0) {
        for (int g = 0; g <= b; ++g) gstart[g] = 0;
    } else {
        int p = batch[i - 1];
        for (int g = p + 1; g <= b; ++g) gstart[g] = i;
    }
    if (i == n - 1) {
        for (int g = b + 1; g <= NGRAPH; ++g) gstart[g] = n;
    }
}

// ---- global mean pool: segmented gather of bf16 h, LDS reduce, few atomics ----
__global__ __launch_bounds__(256) void pool_kernel(const unsigned short* __restrict__ h,
                                                   const int* __restrict__ gstart,
                                                   float* __restrict__ sums) {
    __shared__ float4 buf[8][32];
    const int g = blockIdx.x;       // graph
    const int split = blockIdx.y;   // 0..7
    const int t = threadIdx.x;
    const int c32 = t & 31;
    const int c = c32 << 2;
    const int r = t >> 5;           // 0..7
    int s0 = gstart[g], s1 = gstart[g + 1];
    int len = s1 - s0;
    int chunk = (len + 7) >> 3;
    int a = s0 + split * chunk;
    int b = min(a + chunk, s1);
    float4 acc = make_float4(0.f, 0.f, 0.f, 0.f);
    for (int i = a + r; i < b; i += 8) {
        ushort4 v = *(const ushort4*)(h + (size_t)i * H + c);
        acc.x += bf2f(v.x); acc.y += bf2f(v.y); acc.z += bf2f(v.z); acc.w += bf2f(v.w);
    }
    buf[r][c32] = acc;
    __syncthreads();
    if (r == 0) {
        float4 s = buf[0][c32];
        #pragma unroll
        for (int k = 1; k < 8; ++k) {
            float4 v = buf[k][c32];
            s.x += v.x; s.y += v.y; s.z += v.z; s.w += v.w;
        }
        float* sp = sums + (size_t)g * H + c;
        atomicAdd(sp + 0, s.x);
        atomicAdd(sp + 1, s.y);
        atomicAdd(sp + 2, s.z);
        atomicAdd(sp + 3, s.w);
    }
}

// ---------------- classifier: sigmoid(relu(g@w1+b1)@w2+b2) ----------------
__global__ void cls_kernel(const float* __restrict__ sums, const int* __restrict__ gstart,
                           const float* __restrict__ w1, const float* __restrict__ b1,
                           const float* __restrict__ w2, const float* __restrict__ b2,
                           float* __restrict__ out) {
    int g = blockIdx.x;     // 64 graphs
    int m = threadIdx.x;    // 64 mids
    float cnt = (float)(gstart[g + 1] - gstart[g]);
    float inv = 1.0f / fmaxf(cnt, 1.0f);
    float acc = 0.f;
    for (int k = 0; k < H; ++k) {
        float gk = sums[(size_t)g * H + k] * inv;
        acc += gk * w1[(size_t)k * 64 + m];
    }
    float tm = fmaxf(acc + b1[m], 0.f);
    float p = tm * w2[m];
    #pragma unroll
    for (int off = 32; off > 0; off >>= 1) p += __shfl_down(p, off, 64);
    if (m == 0) out[g] = 1.f / (1.f + expf(-(p + b2[0])));
}

extern "C" void kernel_launch(void* const* d_in, const int* in_sizes, int n_in,
                              void* d_out, int out_size, void* d_ws, size_t ws_size,
                              hipStream_t stream) {
    const float* x      = (const float*)d_in[0];
    const int*   ei     = (const int*)d_in[1];
    const float* ea     = (const float*)d_in[2];
    const int*   batch  = (const int*)d_in[3];
    const float* enc_w  = (const float*)d_in[4];
    const float* enc_b  = (const float*)d_in[5];
    const float* edge_w = (const float*)d_in[6];
    const float* edge_b = (const float*)d_in[7];
    const float* eps    = (const float*)d_in[8];
    const float* mlp_w1 = (const float*)d_in[9];
    const float* mlp_b1 = (const float*)d_in[10];
    const float* mlp_w2 = (const float*)d_in[11];
    const float* mlp_b2 = (const float*)d_in[12];
    const float* bn_g   = (const float*)d_in[13];
    const float* bn_b   = (const float*)d_in[14];
    const float* bn_m   = (const float*)d_in[15];
    const float* bn_v   = (const float*)d_in[16];
    const float* cls_w1 = (const float*)d_in[17];
    const float* cls_b1 = (const float*)d_in[18];
    const float* cls_w2 = (const float*)d_in[19];
    const float* cls_b2 = (const float*)d_in[20];
    float* out = (float*)d_out;

    const int n = in_sizes[0];        // 100000
    const int ne = in_sizes[2];       // 1600000
    const int nb = (n + 1023) / 1024; // scan blocks

    // workspace layout (regions kept 16B-aligned)
    unsigned short* hb  = (unsigned short*)d_ws;                    // N*H bf16
    unsigned short* zb  = hb + (size_t)n * H;                       // N*H bf16
    float* sums         = (float*)(zb + (size_t)n * H);             // G*H
    int*   gstart       = (int*)(sums + (size_t)NGRAPH * H);        // G+4
    int*   deg          = gstart + NGRAPH + 4;                      // N
    int*   start        = deg + n;                                  // N+4
    int*   cursor       = start + n + 4;                            // N
    int*   bsum         = cursor + n;                               // 256
    int*   bscan        = bsum + 256;                               // 256
    unsigned short* w1t = (unsigned short*)(bscan + 256);           // 2*128*128
    unsigned short* w2t = w1t + 2 * 16384;                          // 2*128*128
    int2*  sedge        = (int2*)(w2t + 2 * 16384);                 // E

    hipMemsetAsync(sums, 0, (size_t)NGRAPH * H * sizeof(float), stream);
    hipMemsetAsync(deg, 0, (size_t)n * sizeof(int), stream);
    hipMemsetAsync(cursor, 0, (size_t)n * sizeof(int), stream);

    // weight prep (bf16 transpose) — once per call
    prep_kernel<<<128, 256, 0, stream>>>(mlp_w1, mlp_w2, w1t, w2t);

    // ---- counting sort of edges by dst (once; reused both layers) ----
    hist_kernel<<<(ne + 255) / 256, 256, 0, stream>>>(ei, deg, ne);
    scan1_kernel<<<nb, 256, 0, stream>>>(deg, start, bsum, n);
    scan2_kernel<<<1, 256, 0, stream>>>(bsum, bscan, start, nb, n);
    scan3_kernel<<<(n + 255) / 256, 256, 0, stream>>>(start, bscan, n);
    scatter_kernel<<<(ne + 255) / 256, 256, 0, stream>>>(ei, ea, start, cursor, sedge, ne);

    // graph boundaries for pooling
    gbound_kernel<<<(n + 255) / 256, 256, 0, stream>>>(batch, gstart, n);

    // encoder
    {
        int threads = n * 32;
        enc_kernel<<<(threads + 255) / 256, 256, 0, stream>>>(x, enc_w, enc_b, hb, n);
    }

    for (int l = 0; l < NLAYERS; ++l) {
        {
            int threads = n * 64;
            aggregate_kernel<<<(threads + 255) / 256, 256, 0, stream>>>(
                hb, start, sedge, edge_w, edge_b, eps, l, zb, n);
        }
        mfma_mlp_kernel<<<(n + TMM - 1) / TMM, 256, 0, stream>>>(
            hb, zb,
            w1t + (size_t)l * 16384, mlp_b1 + (size_t)l * H,
            w2t + (size_t)l * 16384, mlp_b2 + (size_t)l * H,
            bn_g + (size_t)l * H, bn_b + (size_t)l * H,
            bn_m + (size_t)l * H, bn_v + (size_t)l * H, n);
    }

    pool_kernel<<<dim3(NGRAPH, 8), 256, 0, stream>>>(hb, gstart, sums);
    cls_kernel<<<NGRAPH, 64, 0, stream>>>(sums, gstart, cls_w1, cls_b1, cls_w2, cls_b2, out);
}

// Round 6
// 536.857 us; speedup vs baseline: 12.2846x; 1.0818x over previous
//
#include <hip/hip_runtime.h>
#include <hip/hip_bf16.h>

#define H 128
#define NGRAPH 64
#define NLAYERS 2
#define TMM 64          // rows per MLP block
#define TP 136          // t-tile LDS row stride in bf16 (pad 8)
#define BSH 8           // bucket shift: 256 nodes per bucket
#define MAXB 512        // max buckets (n <= 131072)

typedef short short8 __attribute__((ext_vector_type(8)));
typedef float floatx4 __attribute__((ext_vector_type(4)));

static __device__ __forceinline__ unsigned short f2bf(float v) {
    __hip_bfloat16 b = __float2bfloat16(v);
    return *(unsigned short*)&b;
}
static __device__ __forceinline__ float bf2f(unsigned short u) {
    return __uint_as_float(((unsigned int)u) << 16);
}

// ---------------- encoder: h[i][j] = bf16(x[i]*enc_w[j] + enc_b[j]) ----------------
__global__ void enc_kernel(const float* __restrict__ x, const float* __restrict__ w,
                           const float* __restrict__ b, unsigned short* __restrict__ h, int n) {
    int t = blockIdx.x * blockDim.x + threadIdx.x;
    int i = t >> 5;            // node
    int c = (t & 31) << 2;     // feature*4
    if (i >= n) return;
    float xv = x[i];
    float4 wv = *(const float4*)(w + c);
    float4 bv = *(const float4*)(b + c);
    ushort4 o;
    o.x = f2bf(xv * wv.x + bv.x);
    o.y = f2bf(xv * wv.y + bv.y);
    o.z = f2bf(xv * wv.z + bv.z);
    o.w = f2bf(xv * wv.w + bv.w);
    *(ushort4*)(h + (size_t)i * H + c) = o;
}

// ------- prep: cast+transpose mlp weights to bf16 [l][n][k] -------
__global__ void prep_kernel(const float* __restrict__ w1, const float* __restrict__ w2,
                            unsigned short* __restrict__ w1t, unsigned short* __restrict__ w2t) {
    int idx = blockIdx.x * blockDim.x + threadIdx.x;   // 2*128*128
    int l = idx >> 14;
    int r = idx & 16383;
    int nn = r >> 7;
    int kk = r & 127;
    w1t[(size_t)l * 16384 + nn * 128 + kk] = f2bf(w1[(size_t)l * 16384 + kk * 128 + nn]);
    w2t[(size_t)l * 16384 + nn * 128 + kk] = f2bf(w2[(size_t)l * 16384 + kk * 128 + nn]);
}

// ---------------- counting-sort by dst: histogram ----------------
__global__ void hist_kernel(const int* __restrict__ ei, int* __restrict__ deg, int ne) {
    int e = blockIdx.x * blockDim.x + threadIdx.x;
    if (e >= ne) return;
    atomicAdd(&deg[ei[ne + e]], 1);
}

// -------- hierarchical exclusive scan, level 1: 1024 elems per block --------
__global__ __launch_bounds__(256) void scan1_kernel(const int* __restrict__ deg,
                                                    int* __restrict__ start,
                                                    int* __restrict__ bsum, int n) {
    __shared__ int wsum[4];
    const int t = threadIdx.x;
    const int lane = t & 63;
    const int wid = t >> 6;
    const int base = blockIdx.x * 1024 + t * 4;
    int4 v = make_int4(0, 0, 0, 0);
    if (base + 3 < n) v = *(const int4*)(deg + base);
    else {
        if (base + 0 < n) v.x = deg[base + 0];
        if (base + 1 < n) v.y = deg[base + 1];
        if (base + 2 < n) v.z = deg[base + 2];
    }
    int s = v.x + v.y + v.z + v.w;
    int incl = s;
    #pragma unroll
    for (int off = 1; off < 64; off <<= 1) {
        int u = __shfl_up(incl, off, 64);
        if (lane >= off) incl += u;
    }
    if (lane == 63) wsum[wid] = incl;
    __syncthreads();
    int woff = 0;
    #pragma unroll
    for (int k = 0; k < 4; ++k) if (k < wid) woff += wsum[k];
    int excl = woff + incl - s;
    int4 o;
    o.x = excl;
    o.y = o.x + v.x;
    o.z = o.y + v.y;
    o.w = o.z + v.z;
    if (base + 3 < n) *(int4*)(start + base) = o;
    else {
        if (base + 0 < n) start[base + 0] = o.x;
        if (base + 1 < n) start[base + 1] = o.y;
        if (base + 2 < n) start[base + 2] = o.z;
    }
    if (t == 255) bsum[blockIdx.x] = woff + incl;
}

// -------- scan level 2: scan block sums (nb <= 256), write total to start[n] --
__global__ __launch_bounds__(256) void scan2_kernel(const int* __restrict__ bsum,
                                                    int* __restrict__ bscan,
                                                    int* __restrict__ start, int nb, int n) {
    __shared__ int wsum[4];
    const int t = threadIdx.x;
    const int lane = t & 63;
    const int wid = t >> 6;
    int v = (t < nb) ? bsum[t] : 0;
    int incl = v;
    #pragma unroll
    for (int off = 1; off < 64; off <<= 1) {
        int u = __shfl_up(incl, off, 64);
        if (lane >= off) incl += u;
    }
    if (lane == 63) wsum[wid] = incl;
    __syncthreads();
    int woff = 0;
    #pragma unroll
    for (int k = 0; k < 4; ++k) if (k < wid) woff += wsum[k];
    if (t < nb) bscan[t] = woff + incl - v;
    if (t == 255) start[n] = woff + incl;
}

// -------- scan level 3: add block offsets --------
__global__ void scan3_kernel(int* __restrict__ start, const int* __restrict__ bscan, int n) {
    int i = blockIdx.x * blockDim.x + threadIdx.x;
    if (i < n) start[i] += bscan[i >> 10];
}

// ---- sort phase A: bin edges into 256-node buckets, block-coalesced runs ----
// entry: x = src, y = (attr_bf16 << 16) | local_dst(8b)
__global__ __launch_bounds__(256) void binA_kernel(
    const int* __restrict__ ei, const float* __restrict__ ea,
    const int* __restrict__ start, int* __restrict__ bcursor,
    int2* __restrict__ sedge2, int ne, int n, int nbuck) {
    __shared__ int hist[MAXB];
    __shared__ int gpos[MAXB];
    const int t = threadIdx.x;
    const int e0 = blockIdx.x * 4096;
    for (int k = t; k < MAXB; k += 256) hist[k] = 0;
    __syncthreads();
    int dsts[16];
    #pragma unroll
    for (int k = 0; k < 16; ++k) {
        int e = e0 + k * 256 + t;
        int d = (e < ne) ? ei[ne + e] : -1;
        dsts[k] = d;
        if (d >= 0) atomicAdd(&hist[d >> BSH], 1);
    }
    __syncthreads();
    // reserve one contiguous run per (block,bucket): single global atomic each
    for (int b = t; b < nbuck; b += 256) {
        int c = hist[b];
        gpos[b] = (c > 0) ? (start[b << BSH] + atomicAdd(&bcursor[b], c)) : 0;
    }
    __syncthreads();
    for (int k = t; k < MAXB; k += 256) hist[k] = 0;   // reuse as local cursor
    __syncthreads();
    #pragma unroll
    for (int k = 0; k < 16; ++k) {
        int d = dsts[k];
        if (d >= 0) {
            int e = e0 + k * 256 + t;
            int b = d >> BSH;
            int idx = atomicAdd(&hist[b], 1);
            int2 p;
            p.x = ei[e];
            p.y = ((int)f2bf(ea[e]) << 16) | (d & ((1 << BSH) - 1));
            sedge2[gpos[b] + idx] = p;
        }
    }
}

// ---- sort phase B: exact scatter within bucket (one block per bucket) ----
// output window (~32 KB) owned by one XCD -> L2 merges, exact writeback
__global__ __launch_bounds__(256) void binB_kernel(
    const int2* __restrict__ sedge2, const int* __restrict__ start,
    int2* __restrict__ sedge, int n) {
    __shared__ int lcur[1 << BSH];
    const int node0 = blockIdx.x << BSH;
    const int t = threadIdx.x;
    lcur[t] = 0;
    __syncthreads();
    int s0 = start[node0];
    int s1 = start[min(node0 + (1 << BSH), n)];
    for (int i = s0 + t; i < s1; i += 256) {
        int2 p = sedge2[i];
        int ld = p.y & ((1 << BSH) - 1);
        int idx = atomicAdd(&lcur[ld], 1);
        sedge[start[node0 + ld] + idx] = p;
    }
}

// ---- segment-reduce gather: z[i] = (1+eps)*h[i] + sum_j relu(h[src_j]+e_j) ----
// one wave per node, bf16 h rows (256 B/row gather), f32 accumulate, bf16 z out
__global__ __launch_bounds__(256) void aggregate_kernel(
    const unsigned short* __restrict__ h, const int* __restrict__ start,
    const int2* __restrict__ sedge,
    const float* __restrict__ ew, const float* __restrict__ eb,
    const float* __restrict__ epsp, int layer,
    unsigned short* __restrict__ z, int n) {
    int node = (blockIdx.x * blockDim.x + threadIdx.x) >> 6;
    int lane = threadIdx.x & 63;
    if (node >= n) return;
    int c = lane << 1;
    float2 wv = *(const float2*)(ew + c);
    float2 bv = *(const float2*)(eb + c);
    float2 acc = make_float2(0.f, 0.f);
    int s0 = start[node], s1 = start[node + 1];
    int j = s0;
    for (; j + 8 <= s1; j += 8) {
        int2 e[8];
        ushort2 hv[8];
        #pragma unroll
        for (int k = 0; k < 8; ++k) e[k] = sedge[j + k];
        #pragma unroll
        for (int k = 0; k < 8; ++k)
            hv[k] = *(const ushort2*)(h + (size_t)e[k].x * H + c);
        #pragma unroll
        for (int k = 0; k < 8; ++k) {
            float a = bf2f((unsigned short)(((unsigned int)e[k].y) >> 16));
            acc.x += fmaxf(fmaf(a, wv.x, bv.x) + bf2f(hv[k].x), 0.f);
            acc.y += fmaxf(fmaf(a, wv.y, bv.y) + bf2f(hv[k].y), 0.f);
        }
    }
    for (; j < s1; ++j) {
        int2 e = sedge[j];
        float a = bf2f((unsigned short)(((unsigned int)e.y) >> 16));
        ushort2 hv = *(const ushort2*)(h + (size_t)e.x * H + c);
        acc.x += fmaxf(fmaf(a, wv.x, bv.x) + bf2f(hv.x), 0.f);
        acc.y += fmaxf(fmaf(a, wv.y, bv.y) + bf2f(hv.y), 0.f);
    }
    float ev = 1.0f + epsp[layer];
    ushort2 hv = *(const ushort2*)(h + (size_t)node * H + c);
    ushort2 p;
    p.x = f2bf(fmaf(ev, bf2f(hv.x), acc.x));
    p.y = f2bf(fmaf(ev, bf2f(hv.y), acc.y));
    *(ushort2*)(z + (size_t)node * H + c) = p;
}

// ---- MFMA node MLP: h = bf16(relu(BN(relu(z@w1+b1)@w2+b2))), bf16 in/out ----
__global__ __launch_bounds__(256) void mfma_mlp_kernel(
    unsigned short* __restrict__ h, const unsigned short* __restrict__ z,
    const unsigned short* __restrict__ w1t, const float* __restrict__ b1,
    const unsigned short* __restrict__ w2t, const float* __restrict__ b2,
    const float* __restrict__ gamma, const float* __restrict__ beta,
    const float* __restrict__ mean, const float* __restrict__ var, int n) {
    __shared__ unsigned short ts[TMM * TP];
    const int tid = threadIdx.x;
    const int wid = tid >> 6;
    const int lane = tid & 63;
    const int m = lane & 15;     // A row within 16 / B col
    const int q = lane >> 4;     // quad
    const int row0 = blockIdx.x * TMM + wid * 16;

    // ---------- GEMM1: t = relu(z @ w1 + b1) ----------
    floatx4 acc[8];
    #pragma unroll
    for (int ct = 0; ct < 8; ++ct) acc[ct] = (floatx4)(0.f);

    const unsigned short* zrow = z + (size_t)(row0 + m) * H + q * 8;
    #pragma unroll
    for (int kb = 0; kb < H; kb += 32) {
        short8 a = *(const short8*)(zrow + kb);
        #pragma unroll
        for (int ct = 0; ct < 8; ++ct) {
            short8 b = *(const short8*)(w1t + (size_t)(ct * 16 + m) * H + kb + q * 8);
            acc[ct] = __builtin_amdgcn_mfma_f32_16x16x32_bf16(a, b, acc[ct], 0, 0, 0);
        }
    }
    unsigned short* tw = ts + wid * 16 * TP;
    #pragma unroll
    for (int ct = 0; ct < 8; ++ct) {
        float bb = b1[ct * 16 + m];
        #pragma unroll
        for (int r = 0; r < 4; ++r) {
            float v = fmaxf(acc[ct][r] + bb, 0.f);
            tw[(q * 4 + r) * TP + ct * 16 + m] = f2bf(v);
        }
    }

    // ---------- GEMM2: z2 = t @ w2 + b2, then BN + relu ----------
    floatx4 acc2[8];
    #pragma unroll
    for (int ct = 0; ct < 8; ++ct) acc2[ct] = (floatx4)(0.f);

    const unsigned short* trow = tw + m * TP + q * 8;
    #pragma unroll
    for (int kb = 0; kb < H; kb += 32) {
        short8 a = *(const short8*)(trow + kb);
        #pragma unroll
        for (int ct = 0; ct < 8; ++ct) {
            short8 b = *(const short8*)(w2t + (size_t)(ct * 16 + m) * H + kb + q * 8);
            acc2[ct] = __builtin_amdgcn_mfma_f32_16x16x32_bf16(a, b, acc2[ct], 0, 0, 0);
        }
    }
    #pragma unroll
    for (int ct = 0; ct < 8; ++ct) {
        int col = ct * 16 + m;
        float bb = b2[col];
        float sc = gamma[col] * rsqrtf(var[col] + 1e-5f);
        float mn = mean[col];
        float bt = beta[col];
        #pragma unroll
        for (int r = 0; r < 4; ++r) {
            int grow = row0 + q * 4 + r;
            if (grow < n) {
                float v = fmaxf((acc2[ct][r] + bb - mn) * sc + bt, 0.f);
                h[(size_t)grow * H + col] = f2bf(v);
            }
        }
    }
}

// ---- graph boundaries from sorted batch: gstart[g] = first node of graph g ----
__global__ void gbound_kernel(const int* __restrict__ batch, int* __restrict__ gstart, int n) {
    int i = blockIdx.x * blockDim.x + threadIdx.x;
    if (i >= n) return;
    int b = batch[i];
    if (i == 0) {
        for (int g = 0; g <= b; ++g) gstart[g] = 0;
    } else {
        int p = batch[i - 1];
        for (int g = p + 1; g <= b; ++g) gstart[g] = i;
    }
    if (i == n - 1) {
        for (int g = b + 1; g <= NGRAPH; ++g) gstart[g] = n;
    }
}

// ---- global mean pool: segmented gather of bf16 h, LDS reduce, few atomics ----
__global__ __launch_bounds__(256) void pool_kernel(const unsigned short* __restrict__ h,
                                                   const int* __restrict__ gstart,
                                                   float* __restrict__ sums) {
    __shared__ float4 buf[8][32];
    const int g = blockIdx.x;       // graph
    const int split = blockIdx.y;   // 0..7
    const int t = threadIdx.x;
    const int c32 = t & 31;
    const int c = c32 << 2;
    const int r = t >> 5;           // 0..7
    int s0 = gstart[g], s1 = gstart[g + 1];
    int len = s1 - s0;
    int chunk = (len + 7) >> 3;
    int a = s0 + split * chunk;
    int b = min(a + chunk, s1);
    float4 acc = make_float4(0.f, 0.f, 0.f, 0.f);
    for (int i = a + r; i < b; i += 8) {
        ushort4 v = *(const ushort4*)(h + (size_t)i * H + c);
        acc.x += bf2f(v.x); acc.y += bf2f(v.y); acc.z += bf2f(v.z); acc.w += bf2f(v.w);
    }
    buf[r][c32] = acc;
    __syncthreads();
    if (r == 0) {
        float4 s = buf[0][c32];
        #pragma unroll
        for (int k = 1; k < 8; ++k) {
            float4 v = buf[k][c32];
            s.x += v.x; s.y += v.y; s.z += v.z; s.w += v.w;
        }
        float* sp = sums + (size_t)g * H + c;
        atomicAdd(sp + 0, s.x);
        atomicAdd(sp + 1, s.y);
        atomicAdd(sp + 2, s.z);
        atomicAdd(sp + 3, s.w);
    }
}

// ---------------- classifier: sigmoid(relu(g@w1+b1)@w2+b2) ----------------
__global__ void cls_kernel(const float* __restrict__ sums, const int* __restrict__ gstart,
                           const float* __restrict__ w1, const float* __restrict__ b1,
                           const float* __restrict__ w2, const float* __restrict__ b2,
                           float* __restrict__ out) {
    int g = blockIdx.x;     // 64 graphs
    int m = threadIdx.x;    // 64 mids
    float cnt = (float)(gstart[g + 1] - gstart[g]);
    float inv = 1.0f / fmaxf(cnt, 1.0f);
    float acc = 0.f;
    for (int k = 0; k < H; ++k) {
        float gk = sums[(size_t)g * H + k] * inv;
        acc += gk * w1[(size_t)k * 64 + m];
    }
    float tm = fmaxf(acc + b1[m], 0.f);
    float p = tm * w2[m];
    #pragma unroll
    for (int off = 32; off > 0; off >>= 1) p += __shfl_down(p, off, 64);
    if (m == 0) out[g] = 1.f / (1.f + expf(-(p + b2[0])));
}

extern "C" void kernel_launch(void* const* d_in, const int* in_sizes, int n_in,
                              void* d_out, int out_size, void* d_ws, size_t ws_size,
                              hipStream_t stream) {
    const float* x      = (const float*)d_in[0];
    const int*   ei     = (const int*)d_in[1];
    const float* ea     = (const float*)d_in[2];
    const int*   batch  = (const int*)d_in[3];
    const float* enc_w  = (const float*)d_in[4];
    const float* enc_b  = (const float*)d_in[5];
    const float* edge_w = (const float*)d_in[6];
    const float* edge_b = (const float*)d_in[7];
    const float* eps    = (const float*)d_in[8];
    const float* mlp_w1 = (const float*)d_in[9];
    const float* mlp_b1 = (const float*)d_in[10];
    const float* mlp_w2 = (const float*)d_in[11];
    const float* mlp_b2 = (const float*)d_in[12];
    const float* bn_g   = (const float*)d_in[13];
    const float* bn_b   = (const float*)d_in[14];
    const float* bn_m   = (const float*)d_in[15];
    const float* bn_v   = (const float*)d_in[16];
    const float* cls_w1 = (const float*)d_in[17];
    const float* cls_b1 = (const float*)d_in[18];
    const float* cls_w2 = (const float*)d_in[19];
    const float* cls_b2 = (const float*)d_in[20];
    float* out = (float*)d_out;

    const int n = in_sizes[0];        // 100000
    const int ne = in_sizes[2];       // 1600000
    const int nb = (n + 1023) / 1024; // scan blocks
    const int nbuck = (n + (1 << BSH) - 1) >> BSH;  // 256-node buckets

    // workspace layout (regions kept 16B-aligned)
    unsigned short* hb  = (unsigned short*)d_ws;                    // N*H bf16
    unsigned short* zb  = hb + (size_t)n * H;                       // N*H bf16
    float* sums         = (float*)(zb + (size_t)n * H);             // G*H
    int*   gstart       = (int*)(sums + (size_t)NGRAPH * H);        // G+4
    int*   deg          = gstart + NGRAPH + 4;                      // N
    int*   start        = deg + n;                                  // N+4
    int*   bcursor      = start + n + 4;                            // MAXB
    int*   bsum         = bcursor + MAXB;                           // 256
    int*   bscan        = bsum + 256;                               // 256
    unsigned short* w1t = (unsigned short*)(bscan + 256);           // 2*128*128
    unsigned short* w2t = w1t + 2 * 16384;                          // 2*128*128
    int2*  sedge2       = (int2*)(w2t + 2 * 16384);                 // E (binned)
    int2*  sedge        = sedge2 + ne;                              // E (sorted)

    hipMemsetAsync(sums, 0, (size_t)NGRAPH * H * sizeof(float), stream);
    hipMemsetAsync(deg, 0, (size_t)n * sizeof(int), stream);
    hipMemsetAsync(bcursor, 0, (size_t)MAXB * sizeof(int), stream);

    // weight prep (bf16 transpose) — once per call
    prep_kernel<<<128, 256, 0, stream>>>(mlp_w1, mlp_w2, w1t, w2t);

    // ---- counting sort of edges by dst (once; reused both layers) ----
    hist_kernel<<<(ne + 255) / 256, 256, 0, stream>>>(ei, deg, ne);
    scan1_kernel<<<nb, 256, 0, stream>>>(deg, start, bsum, n);
    scan2_kernel<<<1, 256, 0, stream>>>(bsum, bscan, start, nb, n);
    scan3_kernel<<<(n + 255) / 256, 256, 0, stream>>>(start, bscan, n);
    binA_kernel<<<(ne + 4095) / 4096, 256, 0, stream>>>(ei, ea, start, bcursor, sedge2, ne, n, nbuck);
    binB_kernel<<<nbuck, 256, 0, stream>>>(sedge2, start, sedge, n);

    // graph boundaries for pooling
    gbound_kernel<<<(n + 255) / 256, 256, 0, stream>>>(batch, gstart, n);

    // encoder
    {
        int threads = n * 32;
        enc_kernel<<<(threads + 255) / 256, 256, 0, stream>>>(x, enc_w, enc_b, hb, n);
    }

    for (int l = 0; l < NLAYERS; ++l) {
        {
            int threads = n * 64;
            aggregate_kernel<<<(threads + 255) / 256, 256, 0, stream>>>(
                hb, start, sedge, edge_w, edge_b, eps, l, zb, n);
        }
        mfma_mlp_kernel<<<(n + TMM - 1) / TMM, 256, 0, stream>>>(
            hb, zb,
            w1t + (size_t)l * 16384, mlp_b1 + (size_t)l * H,
            w2t + (size_t)l * 16384, mlp_b2 + (size_t)l * H,
            bn_g + (size_t)l * H, bn_b + (size_t)l * H,
            bn_m + (size_t)l * H, bn_v + (size_t)l * H, n);
    }

    pool_kernel<<<dim3(NGRAPH, 8), 256, 0, stream>>>(hb, gstart, sums);
    cls_kernel<<<NGRAPH, 64, 0, stream>>>(sums, gstart, cls_w1, cls_b1, cls_w2, cls_b2, out);
}